// Round 6
// baseline (332.759 us; speedup 1.0000x reference)
//
#include <hip/hip_runtime.h>
#include <hip/hip_bf16.h>

#define BB 2
#define SS 2048
#define HH 2048
#define NHH 16
#define HDD 128

using f32x4  = __attribute__((ext_vector_type(4))) float;
using bf16x8 = __attribute__((ext_vector_type(8))) short;

__device__ __forceinline__ unsigned short f2bf(float x) {
  unsigned int u = __float_as_uint(x);
  unsigned int r = (u + 0x7FFFu + ((u >> 16) & 1u)) >> 16;
  return (unsigned short)r;
}
__device__ __forceinline__ float bf2f(unsigned short u) {
  return __uint_as_float(((unsigned int)u) << 16);
}

__device__ __forceinline__ void gll16(const void* g, void* l) {
  __builtin_amdgcn_global_load_lds(
      (__attribute__((address_space(1))) void*)(g),
      (__attribute__((address_space(3))) void*)(l), 16, 0, 0);
}

#define MFMA16(a, b, c) __builtin_amdgcn_mfma_f32_16x16x32_bf16(a, b, c, 0, 0, 0)

template<int N> __device__ __forceinline__ void wlgkm() {
  static_assert(N == 0 || N == 2 || N == 4 || N == 6 || N == 8 || N == 10 || N == 12,
                "unsupported lgkmcnt");
  if constexpr (N == 0)       asm volatile("s_waitcnt lgkmcnt(0)"  ::: "memory");
  else if constexpr (N == 2)  asm volatile("s_waitcnt lgkmcnt(2)"  ::: "memory");
  else if constexpr (N == 4)  asm volatile("s_waitcnt lgkmcnt(4)"  ::: "memory");
  else if constexpr (N == 6)  asm volatile("s_waitcnt lgkmcnt(6)"  ::: "memory");
  else if constexpr (N == 8)  asm volatile("s_waitcnt lgkmcnt(8)"  ::: "memory");
  else if constexpr (N == 10) asm volatile("s_waitcnt lgkmcnt(10)" ::: "memory");
  else if constexpr (N == 12) asm volatile("s_waitcnt lgkmcnt(12)" ::: "memory");
}
template<int N> __device__ __forceinline__ void wvm() {
  static_assert(N == 0 || N == 5 || N == 6 || N == 7 || N == 8, "unsupported vmcnt");
  if constexpr (N == 0)      asm volatile("s_waitcnt vmcnt(0)" ::: "memory");
  else if constexpr (N == 5) asm volatile("s_waitcnt vmcnt(5)" ::: "memory");
  else if constexpr (N == 6) asm volatile("s_waitcnt vmcnt(6)" ::: "memory");
  else if constexpr (N == 7) asm volatile("s_waitcnt vmcnt(7)" ::: "memory");
  else if constexpr (N == 8) asm volatile("s_waitcnt vmcnt(8)" ::: "memory");
}

// ---------------- converts + rope table ----------------

__global__ void convert_bf16(const float* __restrict__ in, unsigned short* __restrict__ out, int n4) {
  int i = blockIdx.x * blockDim.x + threadIdx.x;
  if (i >= n4) return;
  float4 v = reinterpret_cast<const float4*>(in)[i];
  ushort4 o;
  o.x = f2bf(v.x); o.y = f2bf(v.y); o.z = f2bf(v.z); o.w = f2bf(v.w);
  reinterpret_cast<ushort4*>(out)[i] = o;
}

__global__ void build_tab(float* __restrict__ tab) { // [S][64][2] = cos,sin
  int i = blockIdx.x * blockDim.x + threadIdx.x;
  if (i >= SS * 64) return;
  int s = i >> 6, j = i & 63;
  float invf = expf(-logf(10000.f) * ((float)j / 64.f));
  float a = (float)s * invf;
  tab[i * 2]     = cosf(a);
  tab[i * 2 + 1] = sinf(a);
}

// ---------- QKV GEMM: faithful m201 8-phase template (T2+T3+T4+T5) ----------
// C[M,N] = A[M,K]*W[N,K]^T, BM=BN=256, BK=64, 512 thr = 8 waves (2M x 4N),
// wave tile 128x64. LDS 2-slot dbuf (tile t -> slot t&1), 128 KB.
// Iteration i computes tiles g0=2i (slot0, phases 1-4) and g1=2i+1 (slot1,
// phases 5-8). Each phase: {ds_read subtile JIT; stage 1 half-tile;
// [vmcnt(6) at P4/P8]; barrier; lgkm(0); setprio(1); 16 MFMA; setprio(0);
// barrier}. vmcnt never drains to 0 in steady state (3 half-tiles = 6 loads
// in flight); LAST iter P4 uses vmcnt(0) (guarded-off stages invalidate the
// count - round-4 lesson). Half-tile defs match read phases exactly:
//   A-half0 rows {0-63,128-191} (read P1/P5), A-half1 {64-127,192-255} (P3/P7)
//   B-half0 rows (row&63)<32 (=n01, read P1/P5), B-half1 (row&63)>=32 (P2/P6)
// Stage order P1..P8: t1.B1, t2.A0, t2.B0, t2.A1, t2.B1, t3.A0, t3.B0, t3.A1
// -> every LDS region staged >=1 closing-barrier after its last ds_read
// (register subtiles decouple); per-phase audit in session notes.
// Swizzle: 16B chunk c at c^(row&7), pre-swizzled global src (conflict-free,
// rounds 2-5: SQ_LDS_BANK_CONFLICT = 0).

__global__ __launch_bounds__(512, 1)
void gemm_qkv8(const unsigned short* __restrict__ A,
               const unsigned short* __restrict__ Bw,
               const float* __restrict__ bias,
               unsigned short* __restrict__ outQ,
               unsigned short* __restrict__ outK,
               unsigned short* __restrict__ outV,
               int Kdim) {
  __shared__ unsigned short lA[2][256 * 64];   // 64 KB
  __shared__ unsigned short lB[2][256 * 64];   // 64 KB
  const int tid = threadIdx.x;
  const int tn = blockIdx.x, tm = blockIdx.y;
  const int wid = tid >> 6, lane = tid & 63;
  const int wm = wid >> 2, wn = wid & 3;       // 2 x 4 wave grid
  const int lr = lane & 15, lg = lane >> 4;

  const unsigned short* Ab = A + (size_t)tm * 256 * Kdim;
  const unsigned short* Bb = Bw + (size_t)tn * 256 * Kdim;

  f32x4 acc[8][4] = {};
  bf16x8 af[4][2];      // current A-half fragments
  bf16x8 bfr[4][2];     // current tile's B fragments (n0..n3)

  const int nt  = Kdim >> 6;   // 32
  const int NIT = nt >> 1;     // 16

  auto stA = [&](int t, int h) {               // A-half h: 128 rows, 2 gll/thr
    unsigned short* L = lA[t & 1];
    const int k0 = t << 6;
#pragma unroll
    for (int p = 0; p < 2; ++p) {
      int cl = p * 512 + tid;
      int ri = cl >> 3, c = cl & 7;
      int row = (ri & 63) + ((ri >> 6) << 7) + (h << 6);
      int cg = c ^ (row & 7);
      gll16(Ab + (size_t)row * Kdim + k0 + (cg << 3), L + row * 64 + (c << 3));
    }
  };
  auto stB = [&](int t, int h) {               // B-half h: 128 rows, 2 gll/thr
    unsigned short* L = lB[t & 1];
    const int k0 = t << 6;
#pragma unroll
    for (int p = 0; p < 2; ++p) {
      int cl = p * 512 + tid;
      int ri = cl >> 3, c = cl & 7;
      int row = ((ri >> 5) << 6) + (h << 5) + (ri & 31);
      int cg = c ^ (row & 7);
      gll16(Bb + (size_t)row * Kdim + k0 + (cg << 3), L + row * 64 + (c << 3));
    }
  };
  auto rdA = [&](int s, int h) {               // af <- A-half h of slot s (8 reads)
    const unsigned short* la = lA[s];
#pragma unroll
    for (int q = 0; q < 4; ++q) {
      int ra = wm * 128 + h * 64 + q * 16 + lr;
      af[q][0] = *reinterpret_cast<const bf16x8*>(la + ra * 64 + ((lg ^ (ra & 7)) << 3));
      af[q][1] = *reinterpret_cast<const bf16x8*>(la + ra * 64 + (((4 + lg) ^ (ra & 7)) << 3));
    }
  };
  auto rdB = [&](int s, int h) {               // bfr[2h..2h+1] <- n-half h (4 reads)
    const unsigned short* lb = lB[s];
#pragma unroll
    for (int j = 0; j < 2; ++j) {
      int ni = h * 2 + j;
      int rb = wn * 64 + ni * 16 + lr;
      bfr[ni][0] = *reinterpret_cast<const bf16x8*>(lb + rb * 64 + ((lg ^ (rb & 7)) << 3));
      bfr[ni][1] = *reinterpret_cast<const bf16x8*>(lb + rb * 64 + (((4 + lg) ^ (rb & 7)) << 3));
    }
  };
  auto cluster = [&](int ah, int bh) {         // 16 MFMA on quadrant (ah,bh)
    __builtin_amdgcn_s_setprio(1);
#pragma unroll
    for (int q = 0; q < 4; ++q)
#pragma unroll
      for (int j = 0; j < 2; ++j) {
        int mi = ah * 4 + q, ni = bh * 2 + j;
        acc[mi][ni] = MFMA16(af[q][0], bfr[ni][0], acc[mi][ni]);
        acc[mi][ni] = MFMA16(af[q][1], bfr[ni][1], acc[mi][ni]);
      }
    __builtin_amdgcn_s_setprio(0);
  };

  // ---- prologue: tile0 all 4 halves + tile1 {A0,B0,A1} = 14 loads.
  stA(0, 0); stB(0, 0); stA(0, 1); stB(0, 1);
  stA(1, 0); stB(1, 0); stA(1, 1);
  wvm<6>();                                    // retire tile0's 4 halves
  __builtin_amdgcn_s_barrier();
  __builtin_amdgcn_sched_barrier(0);

  for (int i = 0; i < NIT; ++i) {
    const int g0 = 2 * i, g1 = 2 * i + 1;

    // P1: reads a0(g0)+n01(g0) | stage t(g1).B1
    rdA(0, 0); rdB(0, 0);
    stB(g1, 1);
    __builtin_amdgcn_s_barrier();
    wlgkm<0>(); __builtin_amdgcn_sched_barrier(0);
    cluster(0, 0);
    __builtin_amdgcn_s_barrier();

    // P2: reads n23(g0) | stage t(g0+2).A0
    rdB(0, 1);
    if (g0 + 2 < nt) stA(g0 + 2, 0);
    __builtin_amdgcn_s_barrier();
    wlgkm<0>(); __builtin_amdgcn_sched_barrier(0);
    cluster(0, 1);
    __builtin_amdgcn_s_barrier();

    // P3: reads a1(g0) | stage t(g0+2).B0
    rdA(0, 1);
    if (g0 + 2 < nt) stB(g0 + 2, 0);
    __builtin_amdgcn_s_barrier();
    wlgkm<0>(); __builtin_amdgcn_sched_barrier(0);
    cluster(1, 0);
    __builtin_amdgcn_s_barrier();

    // P4: no reads | stage t(g0+2).A1 | vmcnt retires tile g1
    if (g0 + 2 < nt) stA(g0 + 2, 1);
    if (i + 1 < NIT) wvm<6>(); else wvm<0>();
    __builtin_amdgcn_s_barrier();
    __builtin_amdgcn_sched_barrier(0);
    cluster(1, 1);
    __builtin_amdgcn_s_barrier();

    // P5: reads a0(g1)+n01(g1) | stage t(g0+2).B1
    rdA(1, 0); rdB(1, 0);
    if (g0 + 2 < nt) stB(g0 + 2, 1);
    __builtin_amdgcn_s_barrier();
    wlgkm<0>(); __builtin_amdgcn_sched_barrier(0);
    cluster(0, 0);
    __builtin_amdgcn_s_barrier();

    // P6: reads n23(g1) | stage t(g1+2).A0
    rdB(1, 1);
    if (g1 + 2 < nt) stA(g1 + 2, 0);
    __builtin_amdgcn_s_barrier();
    wlgkm<0>(); __builtin_amdgcn_sched_barrier(0);
    cluster(0, 1);
    __builtin_amdgcn_s_barrier();

    // P7: reads a1(g1) | stage t(g1+2).B0
    rdA(1, 1);
    if (g1 + 2 < nt) stB(g1 + 2, 0);
    __builtin_amdgcn_s_barrier();
    wlgkm<0>(); __builtin_amdgcn_sched_barrier(0);
    cluster(1, 0);
    __builtin_amdgcn_s_barrier();

    // P8: no reads | stage t(g1+2).A1 | vmcnt retires tile g0+2
    if (g1 + 2 < nt) stA(g1 + 2, 1);
    if (i + 1 < NIT) wvm<6>();
    __builtin_amdgcn_s_barrier();
    __builtin_amdgcn_sched_barrier(0);
    cluster(1, 1);
    __builtin_amdgcn_s_barrier();
  }
  wvm<0>();                                    // drain stragglers before end

  // ---------------- epilogue: bias + Q/K/V split ----------------
#pragma unroll
  for (int mi = 0; mi < 8; ++mi) {
#pragma unroll
    for (int ni = 0; ni < 4; ++ni) {
      int n = tn * 256 + wn * 64 + ni * 16 + lr;
#pragma unroll
      for (int r = 0; r < 4; ++r) {
        int m = tm * 256 + wm * 128 + mi * 16 + lg * 4 + r;
        float v = acc[mi][ni][r] + bias[n];
        int sel = n >> 11;
        int h = (n >> 7) & 15;
        int d = n & 127;
        int b = m >> 11;
        int s = m & 2047;
        if (sel == 0)
          outQ[(((size_t)(b * 16 + h)) * 2048 + s) * 128 + d] = f2bf(v);
        else if (sel == 1)
          outK[(((size_t)(b * 16 + h)) * 2048 + s) * 128 + d] = f2bf(v);
        else
          outV[(((size_t)(b * 16 + h)) * 128 + d) * 2048 + s] = f2bf(v);
      }
    }
  }
}

// ---------- cross-slot pipelined bt-GEMM (kept for the O-projection) ----------

template<int MODE, int MI, int NB>
__global__ __launch_bounds__(512, 1)
void gemm_pipe(const unsigned short* __restrict__ A,
               const unsigned short* __restrict__ Bw,
               const float* __restrict__ bias,
               float* __restrict__ outF,
               unsigned short* __restrict__ outQ,
               unsigned short* __restrict__ outK,
               unsigned short* __restrict__ outV,
               int Kdim) {
  constexpr int BM = 32 * MI;
  constexpr int BN = 64 * NB;
  constexpr int TOPS = 2 * (BM / 128) + NB;   // vmem ops staged per K-tile
  __shared__ unsigned short lA[2][BM * 64];
  __shared__ unsigned short lB[2][BN * 64];
  const int tid = threadIdx.x;
  const int tn = blockIdx.x, tm = blockIdx.y;
  const int wid = tid >> 6, lane = tid & 63;
  const int wm = wid >> 2, wn = wid & 3;      // 2 x 4 wave grid
  const int lr = lane & 15, lg = lane >> 4;

  const unsigned short* Ab = A + (size_t)tm * BM * Kdim;
  const unsigned short* Bb = Bw + (size_t)tn * BN * Kdim;

  f32x4 acc[MI][NB] = {};
  bf16x8 af[MI][2], bfr[NB][2];

  const int nt = Kdim >> 6;

  auto stageA = [&](int t, int h) {          // half-tile: BM/2 rows
    unsigned short* L = lA[t & 1];
    const int k0 = t << 6;
#pragma unroll
    for (int p = 0; p < BM / 128; ++p) {
      int cl = p * 512 + tid;
      int ri = cl >> 3, c = cl & 7;
      int row = (ri / (8 * MI)) * (16 * MI) + h * (8 * MI) + (ri % (8 * MI));
      int cg = c ^ (row & 7);
      gll16(Ab + (size_t)row * Kdim + k0 + (cg << 3), L + row * 64 + (c << 3));
    }
  };
  auto stageB = [&](int t, int h) {          // 1/NB-tile: 64 rows (4 wn x 16)
    unsigned short* L = lB[t & 1];
    const int k0 = t << 6;
    int cl = tid;
    int ri = cl >> 3, c = cl & 7;
    int row = (ri >> 4) * (16 * NB) + h * 16 + (ri & 15);
    int cg = c ^ (row & 7);
    gll16(Bb + (size_t)row * Kdim + k0 + (cg << 3), L + row * 64 + (c << 3));
  };
  auto readAhalf = [&](int g, int h) {       // MI ds_reads
    const unsigned short* la = lA[g & 1];
#pragma unroll
    for (int mi = h * (MI / 2); mi < (h + 1) * (MI / 2); ++mi) {
      int ra = wm * (BM / 2) + mi * 16 + lr;
      af[mi][0] = *reinterpret_cast<const bf16x8*>(la + ra * 64 + ((lg ^ (ra & 7)) << 3));
      af[mi][1] = *reinterpret_cast<const bf16x8*>(la + ra * 64 + (((4 + lg) ^ (ra & 7)) << 3));
    }
  };
  auto readB = [&](int g, int ni) {          // 2 ds_reads
    const unsigned short* lb = lB[g & 1];
    int rb = wn * (16 * NB) + ni * 16 + lr;
    bfr[ni][0] = *reinterpret_cast<const bf16x8*>(lb + rb * 64 + ((lg ^ (rb & 7)) << 3));
    bfr[ni][1] = *reinterpret_cast<const bf16x8*>(lb + rb * 64 + (((4 + lg) ^ (rb & 7)) << 3));
  };
  auto quad = [&](int ah, int ni) {          // 8 MFMA
    __builtin_amdgcn_s_setprio(1);
#pragma unroll
    for (int mi = ah * (MI / 2); mi < (ah + 1) * (MI / 2); ++mi) {
      acc[mi][ni] = MFMA16(af[mi][0], bfr[ni][0], acc[mi][ni]);
      acc[mi][ni] = MFMA16(af[mi][1], bfr[ni][1], acc[mi][ni]);
    }
    __builtin_amdgcn_s_setprio(0);
  };

  // ---- prologue: stage tiles 0 and 1; retire tile 0; preload its frags.
  stageA(0, 0); stageA(0, 1);
#pragma unroll
  for (int h = 0; h < NB; ++h) stageB(0, h);
  stageA(1, 0); stageA(1, 1);
#pragma unroll
  for (int h = 0; h < NB; ++h) stageB(1, h);
  wvm<TOPS>();                                // retire ALL of tile 0's stages
  __builtin_amdgcn_s_barrier();
  __builtin_amdgcn_sched_barrier(0);
  readAhalf(0, 0);
#pragma unroll
  for (int ni = 0; ni < NB - 1; ++ni) readB(0, ni);

  for (int g = 0; g < nt; ++g) {
    // ---- a0 x n0: prefetch last B group of this tile
    readB(g, NB - 1);
    wlgkm<2 * (NB - 1)>();                    // drain af03(g)+bfr0(g)
    __builtin_amdgcn_sched_barrier(0);
    quad(0, 0);

    // ---- a0 x n1: prefetch af47(g)
    readAhalf(g, 1);
    wlgkm<2 * (NB - 2) + MI>();               // drain bfr1(g)
    __builtin_amdgcn_sched_barrier(0);
    quad(0, 1);

    if constexpr (NB == 4) {
      wlgkm<2 + MI>();                        // drain bfr2(g)
      __builtin_amdgcn_sched_barrier(0);
      quad(0, 2);
    }

    // ---- a0 x n(NB-1)
    wlgkm<MI>();                              // drain bfr[NB-1](g)
    __builtin_amdgcn_sched_barrier(0);
    quad(0, NB - 1);

    // ---- a1 x n0: tile boundary (single barrier per tile)
    asm volatile("s_waitcnt vmcnt(0) lgkmcnt(0)" ::: "memory");
    __builtin_amdgcn_s_barrier();
    __builtin_amdgcn_sched_barrier(0);
    if (g + 1 < nt) readAhalf(g + 1, 0);                   // slot (g+1)&1
    if (g + 2 < nt) { stageA(g + 2, 0); stageA(g + 2, 1); } // slot g&1
    quad(1, 0);

    // ---- a1 x n1: stage all B(g+2)
    if (g + 1 < nt) readB(g + 1, 0);
    if (g + 2 < nt) {
#pragma unroll
      for (int h = 0; h < NB; ++h) stageB(g + 2, h);
    }
    quad(1, 1);

    // ---- a1 x nj, j >= 2
    if (g + 1 < nt) readB(g + 1, 1);
    quad(1, 2);
    if constexpr (NB == 4) {
      if (g + 1 < nt) readB(g + 1, 2);
      quad(1, 3);
    }
  }

  // ---------------- epilogue ----------------
#pragma unroll
  for (int mi = 0; mi < MI; ++mi) {
#pragma unroll
    for (int ni = 0; ni < NB; ++ni) {
      int n = tn * BN + wn * (16 * NB) + ni * 16 + lr;
#pragma unroll
      for (int r = 0; r < 4; ++r) {
        int m = tm * BM + wm * (BM / 2) + mi * 16 + lg * 4 + r;
        float v = acc[mi][ni][r];
        if (MODE == 1) {
          v += bias[n];
          int sel = n >> 11;
          int h = (n >> 7) & 15;
          int d = n & 127;
          int b = m >> 11;
          int s = m & 2047;
          if (sel == 0)
            outQ[(((size_t)(b * 16 + h)) * 2048 + s) * 128 + d] = f2bf(v);
          else if (sel == 1)
            outK[(((size_t)(b * 16 + h)) * 2048 + s) * 128 + d] = f2bf(v);
          else
            outV[(((size_t)(b * 16 + h)) * 128 + d) * 2048 + s] = f2bf(v);
        } else {
          outF[(size_t)m * 2048 + n] = v;
        }
      }
    }
  }
}

// ---------------- in-place RoPE on Q,K ----------------

__global__ void rope_inplace(unsigned short* __restrict__ Qr, unsigned short* __restrict__ Kr,
                             const int* __restrict__ pos, const float* __restrict__ tab) {
  int i = blockIdx.x * blockDim.x + threadIdx.x; // 2^20 threads
  if (i >= (1 << 20)) return;
  int jb = i & 7;
  int s  = (i >> 3) & 2047;
  int bh = (i >> 14) & 31;
  int a  = i >> 19;
  unsigned short* base = (a ? Kr : Qr) + (((size_t)bh * 2048 + s) * 128);
  int b = bh >> 4;
  int p = pos[b * 2048 + s];
  bf16x8 x1 = *reinterpret_cast<bf16x8*>(base + jb * 8);
  bf16x8 x2 = *reinterpret_cast<bf16x8*>(base + 64 + jb * 8);
  bf16x8 y1, y2;
#pragma unroll
  for (int t = 0; t < 8; ++t) {
    int j = jb * 8 + t;
    float c  = tab[((size_t)p * 64 + j) * 2];
    float sn = tab[((size_t)p * 64 + j) * 2 + 1];
    float a1 = bf2f((unsigned short)x1[t]);
    float a2 = bf2f((unsigned short)x2[t]);
    y1[t] = (short)f2bf(a1 * c - a2 * sn);
    y2[t] = (short)f2bf(a2 * c + a1 * sn);
  }
  *reinterpret_cast<bf16x8*>(base + jb * 8) = y1;
  *reinterpret_cast<bf16x8*>(base + 64 + jb * 8) = y2;
}

// ---------------- flash attention (causal, work-balanced) ----------------
// Block bx handles q-tiles {31-bx, bx}: every block does exactly 33 K-iters.
// K/V double-buffered; stage(kt+1) issued before compute(kt); counted
// vmcnt(8) retires exactly stage(kt); raw s_barrier (no full drain).

__global__ __launch_bounds__(256)
void attn_fwd(const unsigned short* __restrict__ Qr,
              const unsigned short* __restrict__ Kr,
              const unsigned short* __restrict__ Vt,
              unsigned short* __restrict__ attnb) {
  __shared__ unsigned short Ks[2][64 * 128];
  __shared__ unsigned short Vs[2][128 * 64];
  __shared__ unsigned short Ps[64 * 64];
  const int bx = blockIdx.x, bh = blockIdx.y;
  const int tid = threadIdx.x;
  const int wid = tid >> 6, lane = tid & 63;
  const int lr = lane & 15, lg = lane >> 4;
  const unsigned short* Qb = Qr + (size_t)bh * SS * HDD;
  const unsigned short* Kb = Kr + (size_t)bh * SS * HDD;
  const unsigned short* Vb = Vt + (size_t)bh * HDD * SS;
  const int b = bh >> 4, h = bh & 15;

  auto stage = [&](int kt, int buf) {        // 8 gll per thread
#pragma unroll
    for (int ch = 0; ch < 4; ++ch) {
      int c = tid + ch * 256;
      {
        int row = c >> 4, cb = c & 15;
        gll16(Kb + ((size_t)(kt * 64 + row)) * 128 + ((cb ^ (row & 7)) << 3), Ks[buf] + c * 8);
      }
      {
        int row = c >> 3, cb = c & 7;
        gll16(Vb + (size_t)row * SS + kt * 64 + ((cb ^ (row & 7)) << 3), Vs[buf] + c * 8);
      }
    }
  };

#pragma unroll 1
  for (int qi = 0; qi < 2; ++qi) {
    const int qt = qi ? bx : (31 - bx);

    bf16x8 qf[4];
#pragma unroll
    for (int kk = 0; kk < 4; ++kk)
      qf[kk] = *reinterpret_cast<const bf16x8*>(
          Qb + ((size_t)(qt * 64 + wid * 16 + lr)) * 128 + kk * 32 + lg * 8);

    f32x4 oacc[8] = {};
    float mrow[4], lsum[4];
#pragma unroll
    for (int r = 0; r < 4; ++r) { mrow[r] = -1e30f; lsum[r] = 0.f; }

    int cur = 0;
    stage(0, 0);

#pragma unroll 1
    for (int kt = 0; kt <= qt; ++kt) {
      if (kt < qt) {
        stage(kt + 1, cur ^ 1);
        asm volatile("s_waitcnt vmcnt(8)" ::: "memory");   // retire stage(kt)
      } else {
        asm volatile("s_waitcnt vmcnt(0)" ::: "memory");
      }
      __builtin_amdgcn_s_barrier();
      __builtin_amdgcn_sched_barrier(0);

      float sv[4][4];
#pragma unroll
      for (int nt = 0; nt < 4; ++nt) {
        f32x4 sa = {};
#pragma unroll
        for (int kk = 0; kk < 4; ++kk) {
          int row = nt * 16 + lr;
          bf16x8 kf = *reinterpret_cast<const bf16x8*>(
              Ks[cur] + row * 128 + (((kk * 4 + lg) ^ (row & 7)) << 3));
          sa = __builtin_amdgcn_mfma_f32_16x16x32_bf16(qf[kk], kf, sa, 0, 0, 0);
        }
#pragma unroll
        for (int r = 0; r < 4; ++r) {
          float s = sa[r] * 0.088388347648318447f; // 1/sqrt(128)
          if (kt == qt && (nt * 16 + lr) > (wid * 16 + lg * 4 + r)) s -= 1e9f;
          sv[nt][r] = s;
        }
      }

      float tmax[4];
#pragma unroll
      for (int r = 0; r < 4; ++r)
        tmax[r] = fmaxf(fmaxf(sv[0][r], sv[1][r]), fmaxf(sv[2][r], sv[3][r]));
#pragma unroll
      for (int r = 0; r < 4; ++r) {
        tmax[r] = fmaxf(tmax[r], __shfl_xor(tmax[r], 1));
        tmax[r] = fmaxf(tmax[r], __shfl_xor(tmax[r], 2));
        tmax[r] = fmaxf(tmax[r], __shfl_xor(tmax[r], 4));
        tmax[r] = fmaxf(tmax[r], __shfl_xor(tmax[r], 8));
      }
      float fr[4], tsum[4];
#pragma unroll
      for (int r = 0; r < 4; ++r) {
        float mn = fmaxf(mrow[r], tmax[r]);
        fr[r] = __expf(mrow[r] - mn);
        mrow[r] = mn;
        tsum[r] = 0.f;
      }
#pragma unroll
      for (int nt = 0; nt < 4; ++nt) {
        int colc = nt * 2 + (lr >> 3);
#pragma unroll
        for (int r = 0; r < 4; ++r) {
          float p = __expf(sv[nt][r] - mrow[r]);
          tsum[r] += p;
          int row = wid * 16 + lg * 4 + r;
          Ps[row * 64 + ((colc ^ (row & 7)) << 3) + (lr & 7)] = f2bf(p);
        }
      }
#pragma unroll
      for (int r = 0; r < 4; ++r) {
        tsum[r] += __shfl_xor(tsum[r], 1);
        tsum[r] += __shfl_xor(tsum[r], 2);
        tsum[r] += __shfl_xor(tsum[r], 4);
        tsum[r] += __shfl_xor(tsum[r], 8);
        lsum[r] = lsum[r] * fr[r] + tsum[r];
      }
#pragma unroll
      for (int ct = 0; ct < 8; ++ct)
#pragma unroll
        for (int r = 0; r < 4; ++r)
          oacc[ct][r] *= fr[r];

      bf16x8 pf[2];
#pragma unroll
      for (int ks = 0; ks < 2; ++ks) {
        int row = wid * 16 + lr;
        pf[ks] = *reinterpret_cast<const bf16x8*>(
            Ps + row * 64 + (((ks * 4 + lg) ^ (row & 7)) << 3));
      }
#pragma unroll
      for (int ct = 0; ct < 8; ++ct) {
#pragma unroll
        for (int ks = 0; ks < 2; ++ks) {
          int row = ct * 16 + lr;
          bf16x8 vf = *reinterpret_cast<const bf16x8*>(
              Vs[cur] + row * 64 + (((ks * 4 + lg) ^ (row & 7)) << 3));
          oacc[ct] = __builtin_amdgcn_mfma_f32_16x16x32_bf16(pf[ks], vf, oacc[ct], 0, 0, 0);
        }
      }
      __builtin_amdgcn_s_barrier();           // readers of buf 'cur' done
      cur ^= 1;
    }

#pragma unroll
    for (int r = 0; r < 4; ++r) {
      float rl = 1.f / lsum[r];
      int qg = qt * 64 + wid * 16 + lg * 4 + r;
#pragma unroll
      for (int ct = 0; ct < 8; ++ct) {
        int d = ct * 16 + lr;
        attnb[((size_t)b * SS + qg) * HH + h * 128 + d] = f2bf(oacc[ct][r] * rl);
      }
    }
  }
}

// ---------------- launch ----------------

extern "C" void kernel_launch(void* const* d_in, const int* in_sizes, int n_in,
                              void* d_out, int out_size, void* d_ws, size_t ws_size,
                              hipStream_t stream) {
  const float* hs     = (const float*)d_in[0];
  const int*   pos    = (const int*)d_in[1];
  const float* qkv_w  = (const float*)d_in[3];
  const float* qkv_b  = (const float*)d_in[4];
  const float* o_w    = (const float*)d_in[5];
  float* out = (float*)d_out;
  char* ws = (char*)d_ws;

  unsigned short* hsb   = (unsigned short*)(ws);                  // 16 MB
  unsigned short* wqkvb = (unsigned short*)(ws + 16777216);       // 24 MB
  unsigned short* owb   = (unsigned short*)(ws + 41943040);       // 8 MB
  unsigned short* Qr    = (unsigned short*)(ws + 50331648);       // 16 MB
  unsigned short* Kr    = (unsigned short*)(ws + 67108864);       // 16 MB
  unsigned short* Vt    = (unsigned short*)(ws + 83886080);       // 16 MB
  unsigned short* attnb = (unsigned short*)(ws + 100663296);      // 16 MB
  float*          tab   = (float*)(ws + 117440512);               // 1 MB

  convert_bf16<<<2097152 / 256, 256, 0, stream>>>(hs, hsb, 2097152);
  convert_bf16<<<3145728 / 256, 256, 0, stream>>>(qkv_w, wqkvb, 3145728);
  convert_bf16<<<1048576 / 256, 256, 0, stream>>>(o_w, owb, 1048576);
  build_tab<<<512, 256, 0, stream>>>(tab);

  // QKV: 256x256 8-phase template, grid 24x16 = 384 blocks.
  gemm_qkv8<<<dim3(24, 16), 512, 0, stream>>>(hsb, wqkvb, qkv_b, Qr, Kr, Vt, 2048);
  rope_inplace<<<4096, 256, 0, stream>>>(Qr, Kr, pos, tab);
  attn_fwd<<<dim3(16, 32), 256, 0, stream>>>(Qr, Kr, Vt, attnb);
  // O-proj: BM=128, BN=256 -> grid 8x32 = 256 blocks = exactly 1 round.
  gemm_pipe<0, 4, 4><<<dim3(8, 32), 512, 0, stream>>>(attnb, owb, nullptr, out, nullptr, nullptr, nullptr, 2048);
}

// Round 7
// 329.591 us; speedup vs baseline: 1.0096x; 1.0096x over previous
//
#include <hip/hip_runtime.h>
#include <hip/hip_bf16.h>

#define BB 2
#define SS 2048
#define HH 2048
#define NHH 16
#define HDD 128

using f32x4  = __attribute__((ext_vector_type(4))) float;
using bf16x8 = __attribute__((ext_vector_type(8))) short;

__device__ __forceinline__ unsigned short f2bf(float x) {
  unsigned int u = __float_as_uint(x);
  unsigned int r = (u + 0x7FFFu + ((u >> 16) & 1u)) >> 16;
  return (unsigned short)r;
}
__device__ __forceinline__ float bf2f(unsigned short u) {
  return __uint_as_float(((unsigned int)u) << 16);
}

__device__ __forceinline__ void gll16(const void* g, void* l) {
  __builtin_amdgcn_global_load_lds(
      (__attribute__((address_space(1))) void*)(g),
      (__attribute__((address_space(3))) void*)(l), 16, 0, 0);
}

#define MFMA16(a, b, c) __builtin_amdgcn_mfma_f32_16x16x32_bf16(a, b, c, 0, 0, 0)

template<int N> __device__ __forceinline__ void wlgkm() {
  static_assert(N == 0 || N == 2 || N == 4 || N == 6 || N == 8 || N == 10 || N == 12,
                "unsupported lgkmcnt");
  if constexpr (N == 0)       asm volatile("s_waitcnt lgkmcnt(0)"  ::: "memory");
  else if constexpr (N == 2)  asm volatile("s_waitcnt lgkmcnt(2)"  ::: "memory");
  else if constexpr (N == 4)  asm volatile("s_waitcnt lgkmcnt(4)"  ::: "memory");
  else if constexpr (N == 6)  asm volatile("s_waitcnt lgkmcnt(6)"  ::: "memory");
  else if constexpr (N == 8)  asm volatile("s_waitcnt lgkmcnt(8)"  ::: "memory");
  else if constexpr (N == 10) asm volatile("s_waitcnt lgkmcnt(10)" ::: "memory");
  else if constexpr (N == 12) asm volatile("s_waitcnt lgkmcnt(12)" ::: "memory");
}
template<int N> __device__ __forceinline__ void wvm() {
  static_assert(N == 0 || N == 5 || N == 6 || N == 7 || N == 8, "unsupported vmcnt");
  if constexpr (N == 0)      asm volatile("s_waitcnt vmcnt(0)" ::: "memory");
  else if constexpr (N == 5) asm volatile("s_waitcnt vmcnt(5)" ::: "memory");
  else if constexpr (N == 6) asm volatile("s_waitcnt vmcnt(6)" ::: "memory");
  else if constexpr (N == 7) asm volatile("s_waitcnt vmcnt(7)" ::: "memory");
  else if constexpr (N == 8) asm volatile("s_waitcnt vmcnt(8)" ::: "memory");
}

// ---------------- converts + rope table ----------------

__global__ void convert_bf16(const float* __restrict__ in, unsigned short* __restrict__ out, int n4) {
  int i = blockIdx.x * blockDim.x + threadIdx.x;
  if (i >= n4) return;
  float4 v = reinterpret_cast<const float4*>(in)[i];
  ushort4 o;
  o.x = f2bf(v.x); o.y = f2bf(v.y); o.z = f2bf(v.z); o.w = f2bf(v.w);
  reinterpret_cast<ushort4*>(out)[i] = o;
}

__global__ void build_tab(float* __restrict__ tab) { // [S][64][2] = cos,sin
  int i = blockIdx.x * blockDim.x + threadIdx.x;
  if (i >= SS * 64) return;
  int s = i >> 6, j = i & 63;
  float invf = expf(-logf(10000.f) * ((float)j / 64.f));
  float a = (float)s * invf;
  tab[i * 2]     = cosf(a);
  tab[i * 2 + 1] = sinf(a);
}

// ---------- QKV GEMM: m97-regime 128x128 tile, TLP-hidden staging ----------
// Session theory (round 6): the 912-TF m97 mechanism is MULTI-BLOCK TLP
// (~3 blocks/CU, waves at different K-phases hide each other's staging) —
// NOT explicit pipelining. Round-0 baseline was in this regime but
// VALU-issue-bound (~100 VALU/step of re-computed staging addresses x 6
// waves/SIMD). This kernel keeps the simple 2-barrier/K-step single-buffer
// loop and removes the VALU bottleneck:
//  - all 16 gll16 src/dst addresses precomputed per-thread; per step the 8
//    global pointers advance by += 64 elements (1 VALU each), LDS dests fixed
//  - ds_read fragment addresses are loop-invariant (single buffer) -> hoisted
//  - BK=64 -> 8-chunk rows, swizzle c^(row&7) conflict-free (BK=32's 4-chunk
//    rows cap at 4-way conflicts; that was the round-0 1.26e7 counter)
// 256 thr = 4 waves (2Mx2N), wave tile 64x64, acc[4][4], 32 MFMA/step,
// LDS 32 KB -> ~3 blocks/CU (VGPR-capped), grid 48x32 = 1536 blocks.

__global__ __launch_bounds__(256)
void gemm_qkv97(const unsigned short* __restrict__ A,
                const unsigned short* __restrict__ Bw,
                const float* __restrict__ bias,
                unsigned short* __restrict__ outQ,
                unsigned short* __restrict__ outK,
                unsigned short* __restrict__ outV,
                int Kdim) {
  __shared__ unsigned short lA[128 * 64];   // 16 KB
  __shared__ unsigned short lB[128 * 64];   // 16 KB
  const int tid = threadIdx.x;
  const int tn = blockIdx.x, tm = blockIdx.y;
  const int wid = tid >> 6, lane = tid & 63;
  const int wm = wid >> 1, wn = wid & 1;    // 2 x 2 wave grid
  const int lr = lane & 15, lg = lane >> 4;

  const unsigned short* Ab = A + (size_t)tm * 128 * Kdim;
  const unsigned short* Bb = Bw + (size_t)tn * 128 * Kdim;

  f32x4 acc[4][4] = {};

  // ---- precomputed staging addresses (the VALU fix) ----
  const unsigned short* sa[4];
  const unsigned short* sb[4];
  unsigned short* da[4];
  unsigned short* db[4];
#pragma unroll
  for (int p = 0; p < 4; ++p) {
    int cl = p * 256 + tid;          // chunk id 0..1023 (16B chunks)
    int ri = cl >> 3, c = cl & 7;
    int cg = c ^ (ri & 7);           // pre-swizzled global source
    sa[p] = Ab + (size_t)ri * Kdim + (cg << 3);
    sb[p] = Bb + (size_t)ri * Kdim + (cg << 3);
    da[p] = lA + ri * 64 + (c << 3);
    db[p] = lB + ri * 64 + (c << 3);
  }

  const int nt = Kdim >> 6;          // 32 K-steps of 64

  for (int k = 0; k < nt; ++k) {
#pragma unroll
    for (int p = 0; p < 4; ++p) {
      gll16(sa[p], da[p]); sa[p] += 64;
      gll16(sb[p], db[p]); sb[p] += 64;
    }
    __syncthreads();                 // drains vmcnt+lgkm, then barrier

    bf16x8 af[4][2], bf[4][2];
#pragma unroll
    for (int t = 0; t < 4; ++t) {
      int ra = wm * 64 + t * 16 + lr;
      int rb = wn * 64 + t * 16 + lr;
      af[t][0] = *reinterpret_cast<const bf16x8*>(lA + ra * 64 + ((lg ^ (ra & 7)) << 3));
      af[t][1] = *reinterpret_cast<const bf16x8*>(lA + ra * 64 + (((4 + lg) ^ (ra & 7)) << 3));
      bf[t][0] = *reinterpret_cast<const bf16x8*>(lB + rb * 64 + ((lg ^ (rb & 7)) << 3));
      bf[t][1] = *reinterpret_cast<const bf16x8*>(lB + rb * 64 + (((4 + lg) ^ (rb & 7)) << 3));
    }
#pragma unroll
    for (int i = 0; i < 4; ++i)
#pragma unroll
      for (int j = 0; j < 4; ++j) {
        acc[i][j] = MFMA16(af[i][0], bf[j][0], acc[i][j]);
        acc[i][j] = MFMA16(af[i][1], bf[j][1], acc[i][j]);
      }
    __syncthreads();                 // readers done before next stage
  }

  // ---------------- epilogue: bias + Q/K/V split ----------------
#pragma unroll
  for (int i = 0; i < 4; ++i) {
#pragma unroll
    for (int j = 0; j < 4; ++j) {
      int n = tn * 128 + wn * 64 + j * 16 + lr;
#pragma unroll
      for (int r = 0; r < 4; ++r) {
        int m = tm * 128 + wm * 64 + i * 16 + lg * 4 + r;
        float v = acc[i][j][r] + bias[n];
        int sel = n >> 11;
        int h = (n >> 7) & 15;
        int d = n & 127;
        int b = m >> 11;
        int s = m & 2047;
        if (sel == 0)
          outQ[(((size_t)(b * 16 + h)) * 2048 + s) * 128 + d] = f2bf(v);
        else if (sel == 1)
          outK[(((size_t)(b * 16 + h)) * 2048 + s) * 128 + d] = f2bf(v);
        else
          outV[(((size_t)(b * 16 + h)) * 128 + d) * 2048 + s] = f2bf(v);
      }
    }
  }
}

// ---------- cross-slot pipelined bt-GEMM (kept for the O-projection) ----------

template<int MODE, int MI, int NB>
__global__ __launch_bounds__(512, 1)
void gemm_pipe(const unsigned short* __restrict__ A,
               const unsigned short* __restrict__ Bw,
               const float* __restrict__ bias,
               float* __restrict__ outF,
               unsigned short* __restrict__ outQ,
               unsigned short* __restrict__ outK,
               unsigned short* __restrict__ outV,
               int Kdim) {
  constexpr int BM = 32 * MI;
  constexpr int BN = 64 * NB;
  constexpr int TOPS = 2 * (BM / 128) + NB;   // vmem ops staged per K-tile
  __shared__ unsigned short lA[2][BM * 64];
  __shared__ unsigned short lB[2][BN * 64];
  const int tid = threadIdx.x;
  const int tn = blockIdx.x, tm = blockIdx.y;
  const int wid = tid >> 6, lane = tid & 63;
  const int wm = wid >> 2, wn = wid & 3;      // 2 x 4 wave grid
  const int lr = lane & 15, lg = lane >> 4;

  const unsigned short* Ab = A + (size_t)tm * BM * Kdim;
  const unsigned short* Bb = Bw + (size_t)tn * BN * Kdim;

  f32x4 acc[MI][NB] = {};
  bf16x8 af[MI][2], bfr[NB][2];

  const int nt = Kdim >> 6;

  auto stageA = [&](int t, int h) {          // half-tile: BM/2 rows
    unsigned short* L = lA[t & 1];
    const int k0 = t << 6;
#pragma unroll
    for (int p = 0; p < BM / 128; ++p) {
      int cl = p * 512 + tid;
      int ri = cl >> 3, c = cl & 7;
      int row = (ri / (8 * MI)) * (16 * MI) + h * (8 * MI) + (ri % (8 * MI));
      int cg = c ^ (row & 7);
      gll16(Ab + (size_t)row * Kdim + k0 + (cg << 3), L + row * 64 + (c << 3));
    }
  };
  auto stageB = [&](int t, int h) {          // 1/NB-tile: 64 rows (4 wn x 16)
    unsigned short* L = lB[t & 1];
    const int k0 = t << 6;
    int cl = tid;
    int ri = cl >> 3, c = cl & 7;
    int row = (ri >> 4) * (16 * NB) + h * 16 + (ri & 15);
    int cg = c ^ (row & 7);
    gll16(Bb + (size_t)row * Kdim + k0 + (cg << 3), L + row * 64 + (c << 3));
  };
  auto readAhalf = [&](int g, int h) {       // MI ds_reads
    const unsigned short* la = lA[g & 1];
#pragma unroll
    for (int mi = h * (MI / 2); mi < (h + 1) * (MI / 2); ++mi) {
      int ra = wm * (BM / 2) + mi * 16 + lr;
      af[mi][0] = *reinterpret_cast<const bf16x8*>(la + ra * 64 + ((lg ^ (ra & 7)) << 3));
      af[mi][1] = *reinterpret_cast<const bf16x8*>(la + ra * 64 + (((4 + lg) ^ (ra & 7)) << 3));
    }
  };
  auto readB = [&](int g, int ni) {          // 2 ds_reads
    const unsigned short* lb = lB[g & 1];
    int rb = wn * (16 * NB) + ni * 16 + lr;
    bfr[ni][0] = *reinterpret_cast<const bf16x8*>(lb + rb * 64 + ((lg ^ (rb & 7)) << 3));
    bfr[ni][1] = *reinterpret_cast<const bf16x8*>(lb + rb * 64 + (((4 + lg) ^ (rb & 7)) << 3));
  };
  auto quad = [&](int ah, int ni) {          // 8 MFMA
    __builtin_amdgcn_s_setprio(1);
#pragma unroll
    for (int mi = ah * (MI / 2); mi < (ah + 1) * (MI / 2); ++mi) {
      acc[mi][ni] = MFMA16(af[mi][0], bfr[ni][0], acc[mi][ni]);
      acc[mi][ni] = MFMA16(af[mi][1], bfr[ni][1], acc[mi][ni]);
    }
    __builtin_amdgcn_s_setprio(0);
  };

  // ---- prologue: stage tiles 0 and 1; retire tile 0; preload its frags.
  stageA(0, 0); stageA(0, 1);
#pragma unroll
  for (int h = 0; h < NB; ++h) stageB(0, h);
  stageA(1, 0); stageA(1, 1);
#pragma unroll
  for (int h = 0; h < NB; ++h) stageB(1, h);
  wvm<TOPS>();                                // retire ALL of tile 0's stages
  __builtin_amdgcn_s_barrier();
  __builtin_amdgcn_sched_barrier(0);
  readAhalf(0, 0);
#pragma unroll
  for (int ni = 0; ni < NB - 1; ++ni) readB(0, ni);

  for (int g = 0; g < nt; ++g) {
    // ---- a0 x n0: prefetch last B group of this tile
    readB(g, NB - 1);
    wlgkm<2 * (NB - 1)>();                    // drain af03(g)+bfr0(g)
    __builtin_amdgcn_sched_barrier(0);
    quad(0, 0);

    // ---- a0 x n1: prefetch af47(g)
    readAhalf(g, 1);
    wlgkm<2 * (NB - 2) + MI>();               // drain bfr1(g)
    __builtin_amdgcn_sched_barrier(0);
    quad(0, 1);

    if constexpr (NB == 4) {
      wlgkm<2 + MI>();                        // drain bfr2(g)
      __builtin_amdgcn_sched_barrier(0);
      quad(0, 2);
    }

    // ---- a0 x n(NB-1)
    wlgkm<MI>();                              // drain bfr[NB-1](g)
    __builtin_amdgcn_sched_barrier(0);
    quad(0, NB - 1);

    // ---- a1 x n0: tile boundary (single barrier per tile)
    asm volatile("s_waitcnt vmcnt(0) lgkmcnt(0)" ::: "memory");
    __builtin_amdgcn_s_barrier();
    __builtin_amdgcn_sched_barrier(0);
    if (g + 1 < nt) readAhalf(g + 1, 0);                   // slot (g+1)&1
    if (g + 2 < nt) { stageA(g + 2, 0); stageA(g + 2, 1); } // slot g&1
    quad(1, 0);

    // ---- a1 x n1: stage all B(g+2)
    if (g + 1 < nt) readB(g + 1, 0);
    if (g + 2 < nt) {
#pragma unroll
      for (int h = 0; h < NB; ++h) stageB(g + 2, h);
    }
    quad(1, 1);

    // ---- a1 x nj, j >= 2
    if (g + 1 < nt) readB(g + 1, 1);
    quad(1, 2);
    if constexpr (NB == 4) {
      if (g + 1 < nt) readB(g + 1, 2);
      quad(1, 3);
    }
  }

  // ---------------- epilogue ----------------
#pragma unroll
  for (int mi = 0; mi < MI; ++mi) {
#pragma unroll
    for (int ni = 0; ni < NB; ++ni) {
      int n = tn * BN + wn * (16 * NB) + ni * 16 + lr;
#pragma unroll
      for (int r = 0; r < 4; ++r) {
        int m = tm * BM + wm * (BM / 2) + mi * 16 + lg * 4 + r;
        float v = acc[mi][ni][r];
        if (MODE == 1) {
          v += bias[n];
          int sel = n >> 11;
          int h = (n >> 7) & 15;
          int d = n & 127;
          int b = m >> 11;
          int s = m & 2047;
          if (sel == 0)
            outQ[(((size_t)(b * 16 + h)) * 2048 + s) * 128 + d] = f2bf(v);
          else if (sel == 1)
            outK[(((size_t)(b * 16 + h)) * 2048 + s) * 128 + d] = f2bf(v);
          else
            outV[(((size_t)(b * 16 + h)) * 128 + d) * 2048 + s] = f2bf(v);
        } else {
          outF[(size_t)m * 2048 + n] = v;
        }
      }
    }
  }
}

// ---------------- in-place RoPE on Q,K ----------------

__global__ void rope_inplace(unsigned short* __restrict__ Qr, unsigned short* __restrict__ Kr,
                             const int* __restrict__ pos, const float* __restrict__ tab) {
  int i = blockIdx.x * blockDim.x + threadIdx.x; // 2^20 threads
  if (i >= (1 << 20)) return;
  int jb = i & 7;
  int s  = (i >> 3) & 2047;
  int bh = (i >> 14) & 31;
  int a  = i >> 19;
  unsigned short* base = (a ? Kr : Qr) + (((size_t)bh * 2048 + s) * 128);
  int b = bh >> 4;
  int p = pos[b * 2048 + s];
  bf16x8 x1 = *reinterpret_cast<bf16x8*>(base + jb * 8);
  bf16x8 x2 = *reinterpret_cast<bf16x8*>(base + 64 + jb * 8);
  bf16x8 y1, y2;
#pragma unroll
  for (int t = 0; t < 8; ++t) {
    int j = jb * 8 + t;
    float c  = tab[((size_t)p * 64 + j) * 2];
    float sn = tab[((size_t)p * 64 + j) * 2 + 1];
    float a1 = bf2f((unsigned short)x1[t]);
    float a2 = bf2f((unsigned short)x2[t]);
    y1[t] = (short)f2bf(a1 * c - a2 * sn);
    y2[t] = (short)f2bf(a2 * c + a1 * sn);
  }
  *reinterpret_cast<bf16x8*>(base + jb * 8) = y1;
  *reinterpret_cast<bf16x8*>(base + 64 + jb * 8) = y2;
}

// ---------------- flash attention (causal, work-balanced) ----------------
// Block bx handles q-tiles {31-bx, bx}: every block does exactly 33 K-iters.
// K/V double-buffered; stage(kt+1) issued before compute(kt); counted
// vmcnt(8) retires exactly stage(kt); raw s_barrier (no full drain).

__global__ __launch_bounds__(256)
void attn_fwd(const unsigned short* __restrict__ Qr,
              const unsigned short* __restrict__ Kr,
              const unsigned short* __restrict__ Vt,
              unsigned short* __restrict__ attnb) {
  __shared__ unsigned short Ks[2][64 * 128];
  __shared__ unsigned short Vs[2][128 * 64];
  __shared__ unsigned short Ps[64 * 64];
  const int bx = blockIdx.x, bh = blockIdx.y;
  const int tid = threadIdx.x;
  const int wid = tid >> 6, lane = tid & 63;
  const int lr = lane & 15, lg = lane >> 4;
  const unsigned short* Qb = Qr + (size_t)bh * SS * HDD;
  const unsigned short* Kb = Kr + (size_t)bh * SS * HDD;
  const unsigned short* Vb = Vt + (size_t)bh * HDD * SS;
  const int b = bh >> 4, h = bh & 15;

  auto stage = [&](int kt, int buf) {        // 8 gll per thread
#pragma unroll
    for (int ch = 0; ch < 4; ++ch) {
      int c = tid + ch * 256;
      {
        int row = c >> 4, cb = c & 15;
        gll16(Kb + ((size_t)(kt * 64 + row)) * 128 + ((cb ^ (row & 7)) << 3), Ks[buf] + c * 8);
      }
      {
        int row = c >> 3, cb = c & 7;
        gll16(Vb + (size_t)row * SS + kt * 64 + ((cb ^ (row & 7)) << 3), Vs[buf] + c * 8);
      }
    }
  };

#pragma unroll 1
  for (int qi = 0; qi < 2; ++qi) {
    const int qt = qi ? bx : (31 - bx);

    bf16x8 qf[4];
#pragma unroll
    for (int kk = 0; kk < 4; ++kk)
      qf[kk] = *reinterpret_cast<const bf16x8*>(
          Qb + ((size_t)(qt * 64 + wid * 16 + lr)) * 128 + kk * 32 + lg * 8);

    f32x4 oacc[8] = {};
    float mrow[4], lsum[4];
#pragma unroll
    for (int r = 0; r < 4; ++r) { mrow[r] = -1e30f; lsum[r] = 0.f; }

    int cur = 0;
    stage(0, 0);

#pragma unroll 1
    for (int kt = 0; kt <= qt; ++kt) {
      if (kt < qt) {
        stage(kt + 1, cur ^ 1);
        asm volatile("s_waitcnt vmcnt(8)" ::: "memory");   // retire stage(kt)
      } else {
        asm volatile("s_waitcnt vmcnt(0)" ::: "memory");
      }
      __builtin_amdgcn_s_barrier();
      __builtin_amdgcn_sched_barrier(0);

      float sv[4][4];
#pragma unroll
      for (int nt = 0; nt < 4; ++nt) {
        f32x4 sa = {};
#pragma unroll
        for (int kk = 0; kk < 4; ++kk) {
          int row = nt * 16 + lr;
          bf16x8 kf = *reinterpret_cast<const bf16x8*>(
              Ks[cur] + row * 128 + (((kk * 4 + lg) ^ (row & 7)) << 3));
          sa = __builtin_amdgcn_mfma_f32_16x16x32_bf16(qf[kk], kf, sa, 0, 0, 0);
        }
#pragma unroll
        for (int r = 0; r < 4; ++r) {
          float s = sa[r] * 0.088388347648318447f; // 1/sqrt(128)
          if (kt == qt && (nt * 16 + lr) > (wid * 16 + lg * 4 + r)) s -= 1e9f;
          sv[nt][r] = s;
        }
      }

      float tmax[4];
#pragma unroll
      for (int r = 0; r < 4; ++r)
        tmax[r] = fmaxf(fmaxf(sv[0][r], sv[1][r]), fmaxf(sv[2][r], sv[3][r]));
#pragma unroll
      for (int r = 0; r < 4; ++r) {
        tmax[r] = fmaxf(tmax[r], __shfl_xor(tmax[r], 1));
        tmax[r] = fmaxf(tmax[r], __shfl_xor(tmax[r], 2));
        tmax[r] = fmaxf(tmax[r], __shfl_xor(tmax[r], 4));
        tmax[r] = fmaxf(tmax[r], __shfl_xor(tmax[r], 8));
      }
      float fr[4], tsum[4];
#pragma unroll
      for (int r = 0; r < 4; ++r) {
        float mn = fmaxf(mrow[r], tmax[r]);
        fr[r] = __expf(mrow[r] - mn);
        mrow[r] = mn;
        tsum[r] = 0.f;
      }
#pragma unroll
      for (int nt = 0; nt < 4; ++nt) {
        int colc = nt * 2 + (lr >> 3);
#pragma unroll
        for (int r = 0; r < 4; ++r) {
          float p = __expf(sv[nt][r] - mrow[r]);
          tsum[r] += p;
          int row = wid * 16 + lg * 4 + r;
          Ps[row * 64 + ((colc ^ (row & 7)) << 3) + (lr & 7)] = f2bf(p);
        }
      }
#pragma unroll
      for (int r = 0; r < 4; ++r) {
        tsum[r] += __shfl_xor(tsum[r], 1);
        tsum[r] += __shfl_xor(tsum[r], 2);
        tsum[r] += __shfl_xor(tsum[r], 4);
        tsum[r] += __shfl_xor(tsum[r], 8);
        lsum[r] = lsum[r] * fr[r] + tsum[r];
      }
#pragma unroll
      for (int ct = 0; ct < 8; ++ct)
#pragma unroll
        for (int r = 0; r < 4; ++r)
          oacc[ct][r] *= fr[r];

      bf16x8 pf[2];
#pragma unroll
      for (int ks = 0; ks < 2; ++ks) {
        int row = wid * 16 + lr;
        pf[ks] = *reinterpret_cast<const bf16x8*>(
            Ps + row * 64 + (((ks * 4 + lg) ^ (row & 7)) << 3));
      }
#pragma unroll
      for (int ct = 0; ct < 8; ++ct) {
#pragma unroll
        for (int ks = 0; ks < 2; ++ks) {
          int row = ct * 16 + lr;
          bf16x8 vf = *reinterpret_cast<const bf16x8*>(
              Vs[cur] + row * 64 + (((ks * 4 + lg) ^ (row & 7)) << 3));
          oacc[ct] = __builtin_amdgcn_mfma_f32_16x16x32_bf16(pf[ks], vf, oacc[ct], 0, 0, 0);
        }
      }
      __builtin_amdgcn_s_barrier();           // readers of buf 'cur' done
      cur ^= 1;
    }

#pragma unroll
    for (int r = 0; r < 4; ++r) {
      float rl = 1.f / lsum[r];
      int qg = qt * 64 + wid * 16 + lg * 4 + r;
#pragma unroll
      for (int ct = 0; ct < 8; ++ct) {
        int d = ct * 16 + lr;
        attnb[((size_t)b * SS + qg) * HH + h * 128 + d] = f2bf(oacc[ct][r] * rl);
      }
    }
  }
}

// ---------------- launch ----------------

extern "C" void kernel_launch(void* const* d_in, const int* in_sizes, int n_in,
                              void* d_out, int out_size, void* d_ws, size_t ws_size,
                              hipStream_t stream) {
  const float* hs     = (const float*)d_in[0];
  const int*   pos    = (const int*)d_in[1];
  const float* qkv_w  = (const float*)d_in[3];
  const float* qkv_b  = (const float*)d_in[4];
  const float* o_w    = (const float*)d_in[5];
  float* out = (float*)d_out;
  char* ws = (char*)d_ws;

  unsigned short* hsb   = (unsigned short*)(ws);                  // 16 MB
  unsigned short* wqkvb = (unsigned short*)(ws + 16777216);       // 24 MB
  unsigned short* owb   = (unsigned short*)(ws + 41943040);       // 8 MB
  unsigned short* Qr    = (unsigned short*)(ws + 50331648);       // 16 MB
  unsigned short* Kr    = (unsigned short*)(ws + 67108864);       // 16 MB
  unsigned short* Vt    = (unsigned short*)(ws + 83886080);       // 16 MB
  unsigned short* attnb = (unsigned short*)(ws + 100663296);      // 16 MB
  float*          tab   = (float*)(ws + 117440512);               // 1 MB

  convert_bf16<<<2097152 / 256, 256, 0, stream>>>(hs, hsb, 2097152);
  convert_bf16<<<3145728 / 256, 256, 0, stream>>>(qkv_w, wqkvb, 3145728);
  convert_bf16<<<1048576 / 256, 256, 0, stream>>>(o_w, owb, 1048576);
  build_tab<<<512, 256, 0, stream>>>(tab);

  // QKV: 128x128 m97-regime, grid 48x32 = 1536 blocks (~3 blocks/CU TLP).
  gemm_qkv97<<<dim3(48, 32), 256, 0, stream>>>(hsb, wqkvb, qkv_b, Qr, Kr, Vt, 2048);
  rope_inplace<<<4096, 256, 0, stream>>>(Qr, Kr, pos, tab);
  attn_fwd<<<dim3(16, 32), 256, 0, stream>>>(Qr, Kr, Vt, attnb);
  // O-proj: BM=128, BN=256 -> grid 8x32 = 256 blocks = exactly 1 round.
  gemm_pipe<0, 4, 4><<<dim3(8, 32), 512, 0, stream>>>(attnb, owb, nullptr, out, nullptr, nullptr, nullptr, 2048);
}

// Round 8
// 309.897 us; speedup vs baseline: 1.0738x; 1.0636x over previous
//
#include <hip/hip_runtime.h>
#include <hip/hip_bf16.h>

#define BB 2
#define SS 2048
#define HH 2048
#define NHH 16
#define HDD 128

using f32x4  = __attribute__((ext_vector_type(4))) float;
using bf16x8 = __attribute__((ext_vector_type(8))) short;

__device__ __forceinline__ unsigned short f2bf(float x) {
  unsigned int u = __float_as_uint(x);
  unsigned int r = (u + 0x7FFFu + ((u >> 16) & 1u)) >> 16;
  return (unsigned short)r;
}
__device__ __forceinline__ float bf2f(unsigned short u) {
  return __uint_as_float(((unsigned int)u) << 16);
}

__device__ __forceinline__ void gll16(const void* g, void* l) {
  __builtin_amdgcn_global_load_lds(
      (__attribute__((address_space(1))) void*)(g),
      (__attribute__((address_space(3))) void*)(l), 16, 0, 0);
}

#define MFMA16(a, b, c) __builtin_amdgcn_mfma_f32_16x16x32_bf16(a, b, c, 0, 0, 0)

template<int N> __device__ __forceinline__ void wlgkm() {
  static_assert(N == 0 || N == 2 || N == 4 || N == 6 || N == 8 || N == 10 || N == 12,
                "unsupported lgkmcnt");
  if constexpr (N == 0)       asm volatile("s_waitcnt lgkmcnt(0)"  ::: "memory");
  else if constexpr (N == 2)  asm volatile("s_waitcnt lgkmcnt(2)"  ::: "memory");
  else if constexpr (N == 4)  asm volatile("s_waitcnt lgkmcnt(4)"  ::: "memory");
  else if constexpr (N == 6)  asm volatile("s_waitcnt lgkmcnt(6)"  ::: "memory");
  else if constexpr (N == 8)  asm volatile("s_waitcnt lgkmcnt(8)"  ::: "memory");
  else if constexpr (N == 10) asm volatile("s_waitcnt lgkmcnt(10)" ::: "memory");
  else if constexpr (N == 12) asm volatile("s_waitcnt lgkmcnt(12)" ::: "memory");
}
template<int N> __device__ __forceinline__ void wvm() {
  static_assert(N == 0 || N == 5 || N == 6 || N == 7 || N == 8, "unsupported vmcnt");
  if constexpr (N == 0)      asm volatile("s_waitcnt vmcnt(0)" ::: "memory");
  else if constexpr (N == 5) asm volatile("s_waitcnt vmcnt(5)" ::: "memory");
  else if constexpr (N == 6) asm volatile("s_waitcnt vmcnt(6)" ::: "memory");
  else if constexpr (N == 7) asm volatile("s_waitcnt vmcnt(7)" ::: "memory");
  else if constexpr (N == 8) asm volatile("s_waitcnt vmcnt(8)" ::: "memory");
}

// ---------------- converts + rope table ----------------

__global__ void convert_bf16(const float* __restrict__ in, unsigned short* __restrict__ out, int n4) {
  int i = blockIdx.x * blockDim.x + threadIdx.x;
  if (i >= n4) return;
  float4 v = reinterpret_cast<const float4*>(in)[i];
  ushort4 o;
  o.x = f2bf(v.x); o.y = f2bf(v.y); o.z = f2bf(v.z); o.w = f2bf(v.w);
  reinterpret_cast<ushort4*>(out)[i] = o;
}

__global__ void build_tab(float* __restrict__ tab) { // [S][64][2] = cos,sin
  int i = blockIdx.x * blockDim.x + threadIdx.x;
  if (i >= SS * 64) return;
  int s = i >> 6, j = i & 63;
  float invf = expf(-logf(10000.f) * ((float)j / 64.f));
  float a = (float)s * invf;
  tab[i * 2]     = cosf(a);
  tab[i * 2 + 1] = sinf(a);
}

// ---------- QKV GEMM: round-3 cross-slot pipeline VERBATIM (measured 140.0 us) ----
// C[M,N] = A[M,K] * W[N,K]^T. 512 threads = 8 waves (2M x 4N).
// BM = 32*MI (=256), BN = 256, BK = 64, 2-slot LDS double buffer.
// One barrier per K-tile; counted lgkm waits; B read in two 2-col groups.

template<int MODE, int MI>
__global__ __launch_bounds__(512, 1)
void gemm_pipe(const unsigned short* __restrict__ A,
               const unsigned short* __restrict__ Bw,
               const float* __restrict__ bias,
               float* __restrict__ outF,
               unsigned short* __restrict__ outQ,
               unsigned short* __restrict__ outK,
               unsigned short* __restrict__ outV,
               int Kdim) {
  constexpr int BM = 32 * MI;                 // 256 (MI=8) or 128 (MI=4)
  __shared__ unsigned short lA[2][BM * 64];
  __shared__ unsigned short lB[2][256 * 64];
  const int tid = threadIdx.x;
  const int tn = blockIdx.x, tm = blockIdx.y;
  const int wid = tid >> 6, lane = tid & 63;
  const int wm = wid >> 2, wn = wid & 3;      // 2 x 4 wave grid
  const int lr = lane & 15, lg = lane >> 4;

  const unsigned short* Ab = A + (size_t)tm * BM * Kdim;
  const unsigned short* Bb = Bw + (size_t)tn * 256 * Kdim;

  f32x4 acc[MI][4] = {};
  bf16x8 af[MI][2], bfr[4][2];

  const int nt = Kdim >> 6;

  auto stageA = [&](int t, int h) {
    unsigned short* L = lA[t & 1];
    const int k0 = t << 6;
#pragma unroll
    for (int p = 0; p < BM / 128; ++p) {
      int cl = p * 512 + tid;
      int ri = cl >> 3, c = cl & 7;
      int row = (ri / (8 * MI)) * (16 * MI) + h * (8 * MI) + (ri % (8 * MI));
      int cg = c ^ (row & 7);
      gll16(Ab + (size_t)row * Kdim + k0 + (cg << 3), L + row * 64 + (c << 3));
    }
  };
  auto stageB = [&](int t, int h) {
    unsigned short* L = lB[t & 1];
    const int k0 = t << 6;
#pragma unroll
    for (int p = 0; p < 2; ++p) {
      int cl = p * 512 + tid;
      int ri = cl >> 3, c = cl & 7;
      int row = (ri >> 5 << 6) + (h << 5) + (ri & 31);
      int cg = c ^ (row & 7);
      gll16(Bb + (size_t)row * Kdim + k0 + (cg << 3), L + row * 64 + (c << 3));
    }
  };
  auto readAhalf = [&](int g, int h) {
    const unsigned short* la = lA[g & 1];
#pragma unroll
    for (int mi = h * (MI / 2); mi < (h + 1) * (MI / 2); ++mi) {
      int ra = wm * (BM / 2) + mi * 16 + lr;
      af[mi][0] = *reinterpret_cast<const bf16x8*>(la + ra * 64 + ((lg ^ (ra & 7)) << 3));
      af[mi][1] = *reinterpret_cast<const bf16x8*>(la + ra * 64 + (((4 + lg) ^ (ra & 7)) << 3));
    }
  };
  auto readBhalf = [&](int g, int h) {
    const unsigned short* lb = lB[g & 1];
#pragma unroll
    for (int ni = h * 2; ni < h * 2 + 2; ++ni) {
      int rb = wn * 64 + ni * 16 + lr;
      bfr[ni][0] = *reinterpret_cast<const bf16x8*>(lb + rb * 64 + ((lg ^ (rb & 7)) << 3));
      bfr[ni][1] = *reinterpret_cast<const bf16x8*>(lb + rb * 64 + (((4 + lg) ^ (rb & 7)) << 3));
    }
  };
  auto quad = [&](int ah, int bh) {
    __builtin_amdgcn_s_setprio(1);
#pragma unroll
    for (int mi = ah * (MI / 2); mi < (ah + 1) * (MI / 2); ++mi)
#pragma unroll
      for (int ni = bh * 2; ni < bh * 2 + 2; ++ni) {
        acc[mi][ni] = MFMA16(af[mi][0], bfr[ni][0], acc[mi][ni]);
        acc[mi][ni] = MFMA16(af[mi][1], bfr[ni][1], acc[mi][ni]);
      }
    __builtin_amdgcn_s_setprio(0);
  };

  // ---- prologue: stage tiles 0 and 1; retire tile 0; preload its frags.
  stageA(0, 0); stageA(0, 1); stageB(0, 0); stageB(0, 1);
  stageA(1, 0); stageA(1, 1); stageB(1, 0); stageB(1, 1);
  if constexpr (MI == 8) wvm<8>();
  else                   wvm<6>();
  __builtin_amdgcn_s_barrier();
  __builtin_amdgcn_sched_barrier(0);
  readAhalf(0, 0);          // af03[0]
  readBhalf(0, 0);          // bfr01[0]

  for (int g = 0; g < nt; ++g) {
    // ---- P0: prefetch bfr23[g]; compute af03 x bfr01
    readBhalf(g, 1);
    wlgkm<4>();                                          // drain af03[g], bfr01[g]
    __builtin_amdgcn_sched_barrier(0);
    quad(0, 0);

    // ---- P1: prefetch af47[g]; compute af03 x bfr23
    readAhalf(g, 1);
    if constexpr (MI == 8) wlgkm<8>(); else wlgkm<4>();  // drain bfr23[g]
    __builtin_amdgcn_sched_barrier(0);
    quad(0, 1);

    // ---- P2: tile boundary (single barrier per K-tile)
    asm volatile("s_waitcnt vmcnt(0) lgkmcnt(0)" ::: "memory");
    __builtin_amdgcn_s_barrier();
    __builtin_amdgcn_sched_barrier(0);
    if (g + 1 < nt) readAhalf(g + 1, 0);                 // af03[g+1], slot (g+1)&1
    if (g + 2 < nt) { stageA(g + 2, 0); stageA(g + 2, 1); }  // slot g&1
    quad(1, 0);

    // ---- P3: prefetch bfr01[g+1]; stage B[g+2]; compute af47 x bfr23
    if (g + 1 < nt) readBhalf(g + 1, 0);                 // slot (g+1)&1
    if (g + 2 < nt) { stageB(g + 2, 0); stageB(g + 2, 1); }  // slot g&1
    quad(1, 1);
  }

  // ---------------- epilogue ----------------
#pragma unroll
  for (int mi = 0; mi < MI; ++mi) {
#pragma unroll
    for (int ni = 0; ni < 4; ++ni) {
      int n = tn * 256 + wn * 64 + ni * 16 + lr;
#pragma unroll
      for (int r = 0; r < 4; ++r) {
        int m = tm * BM + wm * (BM / 2) + mi * 16 + lg * 4 + r;
        float v = acc[mi][ni][r];
        if (MODE == 1) {
          v += bias[n];
          int sel = n >> 11;
          int h = (n >> 7) & 15;
          int d = n & 127;
          int b = m >> 11;
          int s = m & 2047;
          if (sel == 0)
            outQ[(((size_t)(b * 16 + h)) * 2048 + s) * 128 + d] = f2bf(v);
          else if (sel == 1)
            outK[(((size_t)(b * 16 + h)) * 2048 + s) * 128 + d] = f2bf(v);
          else
            outV[(((size_t)(b * 16 + h)) * 128 + d) * 2048 + s] = f2bf(v);
        } else {
          outF[(size_t)m * 2048 + n] = v;
        }
      }
    }
  }
}

// ---------- 128x128 m97-regime GEMM (round-7 kernel, now for the O-proj) ----------
// Simple 2-barrier/K-step single-buffer loop; staging addrs precomputed,
// global ptrs advance +64/step; BK=64 swizzle c^(row&7) conflict-free.
// 256 thr = 4 waves (2Mx2N), 32 KB LDS -> multi-block TLP hides staging.

template<int MODE>
__global__ __launch_bounds__(256)
void gemm97(const unsigned short* __restrict__ A,
            const unsigned short* __restrict__ Bw,
            const float* __restrict__ bias,
            float* __restrict__ outF,
            unsigned short* __restrict__ outQ,
            unsigned short* __restrict__ outK,
            unsigned short* __restrict__ outV,
            int Kdim) {
  __shared__ unsigned short lA[128 * 64];   // 16 KB
  __shared__ unsigned short lB[128 * 64];   // 16 KB
  const int tid = threadIdx.x;
  const int tn = blockIdx.x, tm = blockIdx.y;
  const int wid = tid >> 6, lane = tid & 63;
  const int wm = wid >> 1, wn = wid & 1;    // 2 x 2 wave grid
  const int lr = lane & 15, lg = lane >> 4;

  const unsigned short* Ab = A + (size_t)tm * 128 * Kdim;
  const unsigned short* Bb = Bw + (size_t)tn * 128 * Kdim;

  f32x4 acc[4][4] = {};

  const unsigned short* sa[4];
  const unsigned short* sb[4];
  unsigned short* da[4];
  unsigned short* db[4];
#pragma unroll
  for (int p = 0; p < 4; ++p) {
    int cl = p * 256 + tid;          // chunk id 0..1023 (16B chunks)
    int ri = cl >> 3, c = cl & 7;
    int cg = c ^ (ri & 7);           // pre-swizzled global source
    sa[p] = Ab + (size_t)ri * Kdim + (cg << 3);
    sb[p] = Bb + (size_t)ri * Kdim + (cg << 3);
    da[p] = lA + ri * 64 + (c << 3);
    db[p] = lB + ri * 64 + (c << 3);
  }

  const int nt = Kdim >> 6;          // 32 K-steps of 64

  for (int k = 0; k < nt; ++k) {
#pragma unroll
    for (int p = 0; p < 4; ++p) {
      gll16(sa[p], da[p]); sa[p] += 64;
      gll16(sb[p], db[p]); sb[p] += 64;
    }
    __syncthreads();

    bf16x8 af[4][2], bf[4][2];
#pragma unroll
    for (int t = 0; t < 4; ++t) {
      int ra = wm * 64 + t * 16 + lr;
      int rb = wn * 64 + t * 16 + lr;
      af[t][0] = *reinterpret_cast<const bf16x8*>(lA + ra * 64 + ((lg ^ (ra & 7)) << 3));
      af[t][1] = *reinterpret_cast<const bf16x8*>(lA + ra * 64 + (((4 + lg) ^ (ra & 7)) << 3));
      bf[t][0] = *reinterpret_cast<const bf16x8*>(lB + rb * 64 + ((lg ^ (rb & 7)) << 3));
      bf[t][1] = *reinterpret_cast<const bf16x8*>(lB + rb * 64 + (((4 + lg) ^ (rb & 7)) << 3));
    }
#pragma unroll
    for (int i = 0; i < 4; ++i)
#pragma unroll
      for (int j = 0; j < 4; ++j) {
        acc[i][j] = MFMA16(af[i][0], bf[j][0], acc[i][j]);
        acc[i][j] = MFMA16(af[i][1], bf[j][1], acc[i][j]);
      }
    __syncthreads();
  }

#pragma unroll
  for (int i = 0; i < 4; ++i) {
#pragma unroll
    for (int j = 0; j < 4; ++j) {
      int n = tn * 128 + wn * 64 + j * 16 + lr;
#pragma unroll
      for (int r = 0; r < 4; ++r) {
        int m = tm * 128 + wm * 64 + i * 16 + lg * 4 + r;
        float v = acc[i][j][r];
        if (MODE == 1) {
          v += bias[n];
          int sel = n >> 11;
          int h = (n >> 7) & 15;
          int d = n & 127;
          int b = m >> 11;
          int s = m & 2047;
          if (sel == 0)
            outQ[(((size_t)(b * 16 + h)) * 2048 + s) * 128 + d] = f2bf(v);
          else if (sel == 1)
            outK[(((size_t)(b * 16 + h)) * 2048 + s) * 128 + d] = f2bf(v);
          else
            outV[(((size_t)(b * 16 + h)) * 128 + d) * 2048 + s] = f2bf(v);
        } else {
          outF[(size_t)m * 2048 + n] = v;
        }
      }
    }
  }
}

// ---------------- in-place RoPE on Q,K ----------------

__global__ void rope_inplace(unsigned short* __restrict__ Qr, unsigned short* __restrict__ Kr,
                             const int* __restrict__ pos, const float* __restrict__ tab) {
  int i = blockIdx.x * blockDim.x + threadIdx.x; // 2^20 threads
  if (i >= (1 << 20)) return;
  int jb = i & 7;
  int s  = (i >> 3) & 2047;
  int bh = (i >> 14) & 31;
  int a  = i >> 19;
  unsigned short* base = (a ? Kr : Qr) + (((size_t)bh * 2048 + s) * 128);
  int b = bh >> 4;
  int p = pos[b * 2048 + s];
  bf16x8 x1 = *reinterpret_cast<bf16x8*>(base + jb * 8);
  bf16x8 x2 = *reinterpret_cast<bf16x8*>(base + 64 + jb * 8);
  bf16x8 y1, y2;
#pragma unroll
  for (int t = 0; t < 8; ++t) {
    int j = jb * 8 + t;
    float c  = tab[((size_t)p * 64 + j) * 2];
    float sn = tab[((size_t)p * 64 + j) * 2 + 1];
    float a1 = bf2f((unsigned short)x1[t]);
    float a2 = bf2f((unsigned short)x2[t]);
    y1[t] = (short)f2bf(a1 * c - a2 * sn);
    y2[t] = (short)f2bf(a2 * c + a1 * sn);
  }
  *reinterpret_cast<bf16x8*>(base + jb * 8) = y1;
  *reinterpret_cast<bf16x8*>(base + 64 + jb * 8) = y2;
}

// ---------------- flash attention (causal, work-balanced) ----------------
// Block bx handles q-tiles {31-bx, bx}: every block does exactly 33 K-iters.
// K/V double-buffered; stage(kt+1) issued before compute(kt); counted
// vmcnt(8); raw s_barrier. New this round: hoisted stage pointers
// (advance by +8192/+64 per call) and T13 defer-max (skip O-rescale while
// __all rows' max growth <= 8; p bounded by e^8, f32-accum safe).

__global__ __launch_bounds__(256)
void attn_fwd(const unsigned short* __restrict__ Qr,
              const unsigned short* __restrict__ Kr,
              const unsigned short* __restrict__ Vt,
              unsigned short* __restrict__ attnb) {
  __shared__ unsigned short Ks[2][64 * 128];
  __shared__ unsigned short Vs[2][128 * 64];
  __shared__ unsigned short Ps[64 * 64];
  const int bx = blockIdx.x, bh = blockIdx.y;
  const int tid = threadIdx.x;
  const int wid = tid >> 6, lane = tid & 63;
  const int lr = lane & 15, lg = lane >> 4;
  const unsigned short* Qb = Qr + (size_t)bh * SS * HDD;
  const unsigned short* Kb = Kr + (size_t)bh * SS * HDD;
  const unsigned short* Vb = Vt + (size_t)bh * HDD * SS;
  const int b = bh >> 4, h = bh & 15;

  // hoisted staging addresses (same math as before, kt folded into the ptr)
  const unsigned short* ksrc0[4];
  const unsigned short* vsrc0[4];
  int dst8[4];
#pragma unroll
  for (int ch = 0; ch < 4; ++ch) {
    int c = tid + ch * 256;
    int kr = c >> 4, kc = c & 15;
    ksrc0[ch] = Kb + (size_t)kr * 128 + ((kc ^ (kr & 7)) << 3);
    int vr = c >> 3, vc = c & 7;
    vsrc0[ch] = Vb + (size_t)vr * SS + ((vc ^ (vr & 7)) << 3);
    dst8[ch] = c * 8;
  }
  const unsigned short* ksrc[4];
  const unsigned short* vsrc[4];

  auto stage = [&](int buf) {                // 8 gll per thread, auto-advance kt
#pragma unroll
    for (int ch = 0; ch < 4; ++ch) {
      gll16(ksrc[ch], Ks[buf] + dst8[ch]); ksrc[ch] += 64 * 128;
      gll16(vsrc[ch], Vs[buf] + dst8[ch]); vsrc[ch] += 64;
    }
  };

#pragma unroll 1
  for (int qi = 0; qi < 2; ++qi) {
    const int qt = qi ? bx : (31 - bx);

#pragma unroll
    for (int ch = 0; ch < 4; ++ch) { ksrc[ch] = ksrc0[ch]; vsrc[ch] = vsrc0[ch]; }

    bf16x8 qf[4];
#pragma unroll
    for (int kk = 0; kk < 4; ++kk)
      qf[kk] = *reinterpret_cast<const bf16x8*>(
          Qb + ((size_t)(qt * 64 + wid * 16 + lr)) * 128 + kk * 32 + lg * 8);

    f32x4 oacc[8] = {};
    float mrow[4], lsum[4];
#pragma unroll
    for (int r = 0; r < 4; ++r) { mrow[r] = -1e30f; lsum[r] = 0.f; }

    int cur = 0;
    stage(0);

#pragma unroll 1
    for (int kt = 0; kt <= qt; ++kt) {
      if (kt < qt) {
        stage(cur ^ 1);
        asm volatile("s_waitcnt vmcnt(8)" ::: "memory");   // retire stage(kt)
      } else {
        asm volatile("s_waitcnt vmcnt(0)" ::: "memory");
      }
      __builtin_amdgcn_s_barrier();
      __builtin_amdgcn_sched_barrier(0);

      float sv[4][4];
#pragma unroll
      for (int nt = 0; nt < 4; ++nt) {
        f32x4 sa = {};
#pragma unroll
        for (int kk = 0; kk < 4; ++kk) {
          int row = nt * 16 + lr;
          bf16x8 kf = *reinterpret_cast<const bf16x8*>(
              Ks[cur] + row * 128 + (((kk * 4 + lg) ^ (row & 7)) << 3));
          sa = __builtin_amdgcn_mfma_f32_16x16x32_bf16(qf[kk], kf, sa, 0, 0, 0);
        }
#pragma unroll
        for (int r = 0; r < 4; ++r) {
          float s = sa[r] * 0.088388347648318447f; // 1/sqrt(128)
          if (kt == qt && (nt * 16 + lr) > (wid * 16 + lg * 4 + r)) s -= 1e9f;
          sv[nt][r] = s;
        }
      }

      float tmax[4];
#pragma unroll
      for (int r = 0; r < 4; ++r)
        tmax[r] = fmaxf(fmaxf(sv[0][r], sv[1][r]), fmaxf(sv[2][r], sv[3][r]));
#pragma unroll
      for (int r = 0; r < 4; ++r) {
        tmax[r] = fmaxf(tmax[r], __shfl_xor(tmax[r], 1));
        tmax[r] = fmaxf(tmax[r], __shfl_xor(tmax[r], 2));
        tmax[r] = fmaxf(tmax[r], __shfl_xor(tmax[r], 4));
        tmax[r] = fmaxf(tmax[r], __shfl_xor(tmax[r], 8));
      }

      // ---- T13 defer-max: rescale only when some row's max grew by > 8
      float need = fmaxf(fmaxf(tmax[0] - mrow[0], tmax[1] - mrow[1]),
                         fmaxf(tmax[2] - mrow[2], tmax[3] - mrow[3]));
      if (__any(need > 8.f)) {
#pragma unroll
        for (int r = 0; r < 4; ++r) {
          float mn = fmaxf(mrow[r], tmax[r]);
          float fr = __expf(mrow[r] - mn);
          mrow[r] = mn;
          lsum[r] *= fr;
#pragma unroll
          for (int ct = 0; ct < 8; ++ct) oacc[ct][r] *= fr;
        }
      }

      float tsum[4] = {0.f, 0.f, 0.f, 0.f};
#pragma unroll
      for (int nt = 0; nt < 4; ++nt) {
        int colc = nt * 2 + (lr >> 3);
#pragma unroll
        for (int r = 0; r < 4; ++r) {
          float p = __expf(sv[nt][r] - mrow[r]);
          tsum[r] += p;
          int row = wid * 16 + lg * 4 + r;
          Ps[row * 64 + ((colc ^ (row & 7)) << 3) + (lr & 7)] = f2bf(p);
        }
      }
#pragma unroll
      for (int r = 0; r < 4; ++r) {
        tsum[r] += __shfl_xor(tsum[r], 1);
        tsum[r] += __shfl_xor(tsum[r], 2);
        tsum[r] += __shfl_xor(tsum[r], 4);
        tsum[r] += __shfl_xor(tsum[r], 8);
        lsum[r] += tsum[r];
      }

      bf16x8 pf[2];
#pragma unroll
      for (int ks = 0; ks < 2; ++ks) {
        int row = wid * 16 + lr;
        pf[ks] = *reinterpret_cast<const bf16x8*>(
            Ps + row * 64 + (((ks * 4 + lg) ^ (row & 7)) << 3));
      }
#pragma unroll
      for (int ct = 0; ct < 8; ++ct) {
#pragma unroll
        for (int ks = 0; ks < 2; ++ks) {
          int row = ct * 16 + lr;
          bf16x8 vf = *reinterpret_cast<const bf16x8*>(
              Vs[cur] + row * 64 + (((ks * 4 + lg) ^ (row & 7)) << 3));
          oacc[ct] = __builtin_amdgcn_mfma_f32_16x16x32_bf16(pf[ks], vf, oacc[ct], 0, 0, 0);
        }
      }
      __builtin_amdgcn_s_barrier();           // readers of buf 'cur' done
      cur ^= 1;
    }

#pragma unroll
    for (int r = 0; r < 4; ++r) {
      float rl = 1.f / lsum[r];
      int qg = qt * 64 + wid * 16 + lg * 4 + r;
#pragma unroll
      for (int ct = 0; ct < 8; ++ct) {
        int d = ct * 16 + lr;
        attnb[((size_t)b * SS + qg) * HH + h * 128 + d] = f2bf(oacc[ct][r] * rl);
      }
    }
  }
}

// ---------------- launch ----------------

extern "C" void kernel_launch(void* const* d_in, const int* in_sizes, int n_in,
                              void* d_out, int out_size, void* d_ws, size_t ws_size,
                              hipStream_t stream) {
  const float* hs     = (const float*)d_in[0];
  const int*   pos    = (const int*)d_in[1];
  const float* qkv_w  = (const float*)d_in[3];
  const float* qkv_b  = (const float*)d_in[4];
  const float* o_w    = (const float*)d_in[5];
  float* out = (float*)d_out;
  char* ws = (char*)d_ws;

  unsigned short* hsb   = (unsigned short*)(ws);                  // 16 MB
  unsigned short* wqkvb = (unsigned short*)(ws + 16777216);       // 24 MB
  unsigned short* owb   = (unsigned short*)(ws + 41943040);       // 8 MB
  unsigned short* Qr    = (unsigned short*)(ws + 50331648);       // 16 MB
  unsigned short* Kr    = (unsigned short*)(ws + 67108864);       // 16 MB
  unsigned short* Vt    = (unsigned short*)(ws + 83886080);       // 16 MB
  unsigned short* attnb = (unsigned short*)(ws + 100663296);      // 16 MB
  float*          tab   = (float*)(ws + 117440512);               // 1 MB

  convert_bf16<<<2097152 / 256, 256, 0, stream>>>(hs, hsb, 2097152);
  convert_bf16<<<3145728 / 256, 256, 0, stream>>>(qkv_w, wqkvb, 3145728);
  convert_bf16<<<1048576 / 256, 256, 0, stream>>>(o_w, owb, 1048576);
  build_tab<<<512, 256, 0, stream>>>(tab);

  // QKV: round-3 pipeline, BM=BN=256, grid 24x16 = 384 blocks (measured 140 us).
  gemm_pipe<1, 8><<<dim3(24, 16), 512, 0, stream>>>(hsb, wqkvb, qkv_b, nullptr, Qr, Kr, Vt, 2048);
  rope_inplace<<<4096, 256, 0, stream>>>(Qr, Kr, pos, tab);
  attn_fwd<<<dim3(16, 32), 256, 0, stream>>>(Qr, Kr, Vt, attnb);
  // O-proj: 128x128 m97-regime, grid 16x32 = 512 blocks (multi-block TLP).
  gemm97<0><<<dim3(16, 32), 256, 0, stream>>>(attnb, owb, nullptr, out, nullptr, nullptr, nullptr, 2048);
}

// Round 9
// 281.428 us; speedup vs baseline: 1.1824x; 1.1012x over previous
//
#include <hip/hip_runtime.h>
#include <hip/hip_bf16.h>

#define BB 2
#define SS 2048
#define HH 2048
#define NHH 16
#define HDD 128

using f32x4  = __attribute__((ext_vector_type(4))) float;
using bf16x8 = __attribute__((ext_vector_type(8))) short;

__device__ __forceinline__ unsigned short f2bf(float x) {
  unsigned int u = __float_as_uint(x);
  unsigned int r = (u + 0x7FFFu + ((u >> 16) & 1u)) >> 16;
  return (unsigned short)r;
}
__device__ __forceinline__ float bf2f(unsigned short u) {
  return __uint_as_float(((unsigned int)u) << 16);
}

__device__ __forceinline__ void gll16(const void* g, void* l) {
  __builtin_amdgcn_global_load_lds(
      (__attribute__((address_space(1))) void*)(g),
      (__attribute__((address_space(3))) void*)(l), 16, 0, 0);
}

#define MFMA16(a, b, c) __builtin_amdgcn_mfma_f32_16x16x32_bf16(a, b, c, 0, 0, 0)

template<int N> __device__ __forceinline__ void wlgkm() {
  static_assert(N == 0 || N == 2 || N == 4 || N == 6 || N == 8 || N == 10 || N == 12,
                "unsupported lgkmcnt");
  if constexpr (N == 0)       asm volatile("s_waitcnt lgkmcnt(0)"  ::: "memory");
  else if constexpr (N == 2)  asm volatile("s_waitcnt lgkmcnt(2)"  ::: "memory");
  else if constexpr (N == 4)  asm volatile("s_waitcnt lgkmcnt(4)"  ::: "memory");
  else if constexpr (N == 6)  asm volatile("s_waitcnt lgkmcnt(6)"  ::: "memory");
  else if constexpr (N == 8)  asm volatile("s_waitcnt lgkmcnt(8)"  ::: "memory");
  else if constexpr (N == 10) asm volatile("s_waitcnt lgkmcnt(10)" ::: "memory");
  else if constexpr (N == 12) asm volatile("s_waitcnt lgkmcnt(12)" ::: "memory");
}
template<int N> __device__ __forceinline__ void wvm() {
  static_assert(N == 0 || N == 5 || N == 6 || N == 7 || N == 8, "unsupported vmcnt");
  if constexpr (N == 0)      asm volatile("s_waitcnt vmcnt(0)" ::: "memory");
  else if constexpr (N == 5) asm volatile("s_waitcnt vmcnt(5)" ::: "memory");
  else if constexpr (N == 6) asm volatile("s_waitcnt vmcnt(6)" ::: "memory");
  else if constexpr (N == 7) asm volatile("s_waitcnt vmcnt(7)" ::: "memory");
  else if constexpr (N == 8) asm volatile("s_waitcnt vmcnt(8)" ::: "memory");
}

// ---------------- converts + rope table ----------------

__global__ void convert_bf16(const float* __restrict__ in, unsigned short* __restrict__ out, int n4) {
  int i = blockIdx.x * blockDim.x + threadIdx.x;
  if (i >= n4) return;
  float4 v = reinterpret_cast<const float4*>(in)[i];
  ushort4 o;
  o.x = f2bf(v.x); o.y = f2bf(v.y); o.z = f2bf(v.z); o.w = f2bf(v.w);
  reinterpret_cast<ushort4*>(out)[i] = o;
}

__global__ void build_tab(float* __restrict__ tab) { // [S][64][2] = cos,sin
  int i = blockIdx.x * blockDim.x + threadIdx.x;
  if (i >= SS * 64) return;
  int s = i >> 6, j = i & 63;
  float invf = expf(-logf(10000.f) * ((float)j / 64.f));
  float a = (float)s * invf;
  tab[i * 2]     = cosf(a);
  tab[i * 2 + 1] = sinf(a);
}

// ---------- QKV GEMM: round-3 pipeline (140 us proven) + FUSED RoPE epilogue ----
// C[M,N] = A[M,K]*W[N,K]^T. 512 thr = 8 waves (2Mx4N), BM=BN=256, BK=64,
// 2-slot LDS dbuf, 1 barrier/K-tile, counted lgkm waits (unchanged from r8).
// NEW: rope fused into the epilogue. Block's N-tile holds complete 128-wide
// head strips (tn<8: Q, 8<=tn<16: K, else V). Q/K blocks stage the 256x256
// bf16 output in the (dead) 128 KB LDS with row-XOR swizzle
// col^((row&7)<<3) (involution, both phases), barrier, then each thread
// rope-rotates (d,d+64) bf16x8 pairs and stores vectorized. Kills the
// separate rope_inplace kernel (~64 MB HBM round-trip).

__global__ __launch_bounds__(512, 1)
void gemm_qkv(const unsigned short* __restrict__ A,
              const unsigned short* __restrict__ Bw,
              const float* __restrict__ bias,
              const int* __restrict__ pos,
              const float* __restrict__ tab,
              unsigned short* __restrict__ outQ,
              unsigned short* __restrict__ outK,
              unsigned short* __restrict__ outV,
              int Kdim) {
  __shared__ unsigned short lds_[4][256 * 64];   // lA = slots 0-1, lB = slots 2-3
  const int tid = threadIdx.x;
  const int tn = blockIdx.x, tm = blockIdx.y;
  const int wid = tid >> 6, lane = tid & 63;
  const int wm = wid >> 2, wn = wid & 3;      // 2 x 4 wave grid
  const int lr = lane & 15, lg = lane >> 4;

  const unsigned short* Ab = A + (size_t)tm * 256 * Kdim;
  const unsigned short* Bb = Bw + (size_t)tn * 256 * Kdim;

  f32x4 acc[8][4] = {};
  bf16x8 af[8][2], bfr[4][2];

  const int nt = Kdim >> 6;

  auto stageA = [&](int t, int h) {
    unsigned short* L = lds_[t & 1];
    const int k0 = t << 6;
#pragma unroll
    for (int p = 0; p < 2; ++p) {
      int cl = p * 512 + tid;
      int ri = cl >> 3, c = cl & 7;
      int row = (ri >> 6) * 128 + h * 64 + (ri & 63);
      int cg = c ^ (row & 7);
      gll16(Ab + (size_t)row * Kdim + k0 + (cg << 3), L + row * 64 + (c << 3));
    }
  };
  auto stageB = [&](int t, int h) {
    unsigned short* L = lds_[2 + (t & 1)];
    const int k0 = t << 6;
#pragma unroll
    for (int p = 0; p < 2; ++p) {
      int cl = p * 512 + tid;
      int ri = cl >> 3, c = cl & 7;
      int row = (ri >> 5 << 6) + (h << 5) + (ri & 31);
      int cg = c ^ (row & 7);
      gll16(Bb + (size_t)row * Kdim + k0 + (cg << 3), L + row * 64 + (c << 3));
    }
  };
  auto readAhalf = [&](int g, int h) {
    const unsigned short* la = lds_[g & 1];
#pragma unroll
    for (int mi = h * 4; mi < h * 4 + 4; ++mi) {
      int ra = wm * 128 + mi * 16 + lr;
      af[mi][0] = *reinterpret_cast<const bf16x8*>(la + ra * 64 + ((lg ^ (ra & 7)) << 3));
      af[mi][1] = *reinterpret_cast<const bf16x8*>(la + ra * 64 + (((4 + lg) ^ (ra & 7)) << 3));
    }
  };
  auto readBhalf = [&](int g, int h) {
    const unsigned short* lb = lds_[2 + (g & 1)];
#pragma unroll
    for (int ni = h * 2; ni < h * 2 + 2; ++ni) {
      int rb = wn * 64 + ni * 16 + lr;
      bfr[ni][0] = *reinterpret_cast<const bf16x8*>(lb + rb * 64 + ((lg ^ (rb & 7)) << 3));
      bfr[ni][1] = *reinterpret_cast<const bf16x8*>(lb + rb * 64 + (((4 + lg) ^ (rb & 7)) << 3));
    }
  };
  auto quad = [&](int ah, int bh) {
    __builtin_amdgcn_s_setprio(1);
#pragma unroll
    for (int mi = ah * 4; mi < ah * 4 + 4; ++mi)
#pragma unroll
      for (int ni = bh * 2; ni < bh * 2 + 2; ++ni) {
        acc[mi][ni] = MFMA16(af[mi][0], bfr[ni][0], acc[mi][ni]);
        acc[mi][ni] = MFMA16(af[mi][1], bfr[ni][1], acc[mi][ni]);
      }
    __builtin_amdgcn_s_setprio(0);
  };

  // ---- prologue: stage tiles 0 and 1; retire tile 0; preload its frags.
  stageA(0, 0); stageA(0, 1); stageB(0, 0); stageB(0, 1);
  stageA(1, 0); stageA(1, 1); stageB(1, 0); stageB(1, 1);
  wvm<8>();
  __builtin_amdgcn_s_barrier();
  __builtin_amdgcn_sched_barrier(0);
  readAhalf(0, 0);
  readBhalf(0, 0);

  for (int g = 0; g < nt; ++g) {
    // ---- P0: prefetch bfr23[g]; compute af03 x bfr01
    readBhalf(g, 1);
    wlgkm<4>();
    __builtin_amdgcn_sched_barrier(0);
    quad(0, 0);

    // ---- P1: prefetch af47[g]; compute af03 x bfr23
    readAhalf(g, 1);
    wlgkm<8>();
    __builtin_amdgcn_sched_barrier(0);
    quad(0, 1);

    // ---- P2: tile boundary (single barrier per K-tile)
    asm volatile("s_waitcnt vmcnt(0) lgkmcnt(0)" ::: "memory");
    __builtin_amdgcn_s_barrier();
    __builtin_amdgcn_sched_barrier(0);
    if (g + 1 < nt) readAhalf(g + 1, 0);
    if (g + 2 < nt) { stageA(g + 2, 0); stageA(g + 2, 1); }
    quad(1, 0);

    // ---- P3: prefetch bfr01[g+1]; stage B[g+2]
    if (g + 1 < nt) readBhalf(g + 1, 0);
    if (g + 2 < nt) { stageB(g + 2, 0); stageB(g + 2, 1); }
    quad(1, 1);
  }

  // ---------------- epilogue ----------------
  if (tn < 16) {
    // ---- Q/K block: stage to LDS (row-XOR swizzle), then fused rope + store.
    unsigned short* Ls = &lds_[0][0];           // 256x256 bf16 = 128 KB
    __syncthreads();                            // all K-loop LDS traffic done
#pragma unroll
    for (int mi = 0; mi < 8; ++mi) {
#pragma unroll
      for (int ni = 0; ni < 4; ++ni) {
        int n_l = wn * 64 + ni * 16 + lr;
        float bv = bias[tn * 256 + n_l];
#pragma unroll
        for (int r = 0; r < 4; ++r) {
          int m_l = wm * 128 + mi * 16 + lg * 4 + r;
          Ls[m_l * 256 + (n_l ^ ((m_l & 7) << 3))] = f2bf(acc[mi][ni][r] + bv);
        }
      }
    }
    __syncthreads();

    unsigned short* outX = (tn < 8) ? outQ : outK;
    const int jb = (tid & 7) * 8;               // low-half col block 0..56
    const int r0 = (tid >> 3) * 4;              // 4 rows per thread
#pragma unroll
    for (int rr = 0; rr < 4; ++rr) {
      int row = r0 + rr;
      int m = tm * 256 + row;
      int b = m >> 11, s = m & 2047;
      int p = pos[b * 2048 + s];
      float cs[8], sn[8];
#pragma unroll
      for (int j = 0; j < 8; ++j) {
        float2 t2 = *reinterpret_cast<const float2*>(&tab[((size_t)p * 64 + jb + j) * 2]);
        cs[j] = t2.x; sn[j] = t2.y;
      }
      int swz = (row & 7) << 3;
#pragma unroll
      for (int hb = 0; hb < 2; ++hb) {
        bf16x8 x1 = *reinterpret_cast<const bf16x8*>(&Ls[row * 256 + (hb * 128 + (jb ^ swz))]);
        bf16x8 x2 = *reinterpret_cast<const bf16x8*>(&Ls[row * 256 + (hb * 128 + 64 + (jb ^ swz))]);
        bf16x8 y1, y2;
#pragma unroll
        for (int j = 0; j < 8; ++j) {
          float a1 = bf2f((unsigned short)x1[j]);
          float a2 = bf2f((unsigned short)x2[j]);
          y1[j] = (short)f2bf(a1 * cs[j] - a2 * sn[j]);
          y2[j] = (short)f2bf(a2 * cs[j] + a1 * sn[j]);
        }
        int n0 = tn * 256 + hb * 128;
        int h = (n0 >> 7) & 15;
        unsigned short* dst = outX + (((size_t)(b * 16 + h)) * 2048 + s) * 128;
        *reinterpret_cast<bf16x8*>(&dst[jb]) = y1;
        *reinterpret_cast<bf16x8*>(&dst[64 + jb]) = y2;
      }
    }
  } else {
    // ---- V block: no rope; transposed scalar stores (unchanged).
#pragma unroll
    for (int mi = 0; mi < 8; ++mi) {
#pragma unroll
      for (int ni = 0; ni < 4; ++ni) {
        int n = tn * 256 + wn * 64 + ni * 16 + lr;
        float bv = bias[n];
        int h = (n >> 7) & 15;
        int d = n & 127;
#pragma unroll
        for (int r = 0; r < 4; ++r) {
          int m = tm * 256 + wm * 128 + mi * 16 + lg * 4 + r;
          int b = m >> 11;
          int s = m & 2047;
          outV[(((size_t)(b * 16 + h)) * 128 + d) * 2048 + s] = f2bf(acc[mi][ni][r] + bv);
        }
      }
    }
  }
}

// ---------- 128x128 m97-regime GEMM (O-projection) ----------

template<int MODE>
__global__ __launch_bounds__(256)
void gemm97(const unsigned short* __restrict__ A,
            const unsigned short* __restrict__ Bw,
            float* __restrict__ outF,
            int Kdim) {
  __shared__ unsigned short lA[128 * 64];   // 16 KB
  __shared__ unsigned short lB[128 * 64];   // 16 KB
  const int tid = threadIdx.x;
  const int tn = blockIdx.x, tm = blockIdx.y;
  const int wid = tid >> 6, lane = tid & 63;
  const int wm = wid >> 1, wn = wid & 1;    // 2 x 2 wave grid
  const int lr = lane & 15, lg = lane >> 4;

  const unsigned short* Ab = A + (size_t)tm * 128 * Kdim;
  const unsigned short* Bb = Bw + (size_t)tn * 128 * Kdim;

  f32x4 acc[4][4] = {};

  const unsigned short* sa[4];
  const unsigned short* sb[4];
  unsigned short* da[4];
  unsigned short* db[4];
#pragma unroll
  for (int p = 0; p < 4; ++p) {
    int cl = p * 256 + tid;          // chunk id 0..1023 (16B chunks)
    int ri = cl >> 3, c = cl & 7;
    int cg = c ^ (ri & 7);           // pre-swizzled global source
    sa[p] = Ab + (size_t)ri * Kdim + (cg << 3);
    sb[p] = Bb + (size_t)ri * Kdim + (cg << 3);
    da[p] = lA + ri * 64 + (c << 3);
    db[p] = lB + ri * 64 + (c << 3);
  }

  const int nt = Kdim >> 6;          // K-steps of 64

  for (int k = 0; k < nt; ++k) {
#pragma unroll
    for (int p = 0; p < 4; ++p) {
      gll16(sa[p], da[p]); sa[p] += 64;
      gll16(sb[p], db[p]); sb[p] += 64;
    }
    __syncthreads();

    bf16x8 af[4][2], bf[4][2];
#pragma unroll
    for (int t = 0; t < 4; ++t) {
      int ra = wm * 64 + t * 16 + lr;
      int rb = wn * 64 + t * 16 + lr;
      af[t][0] = *reinterpret_cast<const bf16x8*>(lA + ra * 64 + ((lg ^ (ra & 7)) << 3));
      af[t][1] = *reinterpret_cast<const bf16x8*>(lA + ra * 64 + (((4 + lg) ^ (ra & 7)) << 3));
      bf[t][0] = *reinterpret_cast<const bf16x8*>(lB + rb * 64 + ((lg ^ (rb & 7)) << 3));
      bf[t][1] = *reinterpret_cast<const bf16x8*>(lB + rb * 64 + (((4 + lg) ^ (rb & 7)) << 3));
    }
#pragma unroll
    for (int i = 0; i < 4; ++i)
#pragma unroll
      for (int j = 0; j < 4; ++j) {
        acc[i][j] = MFMA16(af[i][0], bf[j][0], acc[i][j]);
        acc[i][j] = MFMA16(af[i][1], bf[j][1], acc[i][j]);
      }
    __syncthreads();
  }

#pragma unroll
  for (int i = 0; i < 4; ++i) {
#pragma unroll
    for (int j = 0; j < 4; ++j) {
      int n = tn * 128 + wn * 64 + j * 16 + lr;
#pragma unroll
      for (int r = 0; r < 4; ++r) {
        int m = tm * 128 + wm * 64 + i * 16 + lg * 4 + r;
        outF[(size_t)m * 2048 + n] = acc[i][j][r];
      }
    }
  }
}

// ---------------- flash attention (causal, work-balanced) ----------------
// Block bx handles q-tiles {31-bx, bx}: every block does exactly 33 K-iters.
// K/V double-buffered; counted vmcnt(8); raw s_barrier; hoisted stage ptrs;
// T13 defer-max. NEW: exp2-domain softmax (scale*log2e folded; threshold
// 8*log2e = 11.54) — removes the implicit x*log2e mul before each v_exp_f32.

__global__ __launch_bounds__(256)
void attn_fwd(const unsigned short* __restrict__ Qr,
              const unsigned short* __restrict__ Kr,
              const unsigned short* __restrict__ Vt,
              unsigned short* __restrict__ attnb) {
  __shared__ unsigned short Ks[2][64 * 128];
  __shared__ unsigned short Vs[2][128 * 64];
  __shared__ unsigned short Ps[64 * 64];
  const int bx = blockIdx.x, bh = blockIdx.y;
  const int tid = threadIdx.x;
  const int wid = tid >> 6, lane = tid & 63;
  const int lr = lane & 15, lg = lane >> 4;
  const unsigned short* Qb = Qr + (size_t)bh * SS * HDD;
  const unsigned short* Kb = Kr + (size_t)bh * SS * HDD;
  const unsigned short* Vb = Vt + (size_t)bh * HDD * SS;
  const int b = bh >> 4, h = bh & 15;
  const float SC2 = 0.12751763f;               // 1/sqrt(128) * log2(e)

  const unsigned short* ksrc0[4];
  const unsigned short* vsrc0[4];
  int dst8[4];
#pragma unroll
  for (int ch = 0; ch < 4; ++ch) {
    int c = tid + ch * 256;
    int kr = c >> 4, kc = c & 15;
    ksrc0[ch] = Kb + (size_t)kr * 128 + ((kc ^ (kr & 7)) << 3);
    int vr = c >> 3, vc = c & 7;
    vsrc0[ch] = Vb + (size_t)vr * SS + ((vc ^ (vr & 7)) << 3);
    dst8[ch] = c * 8;
  }
  const unsigned short* ksrc[4];
  const unsigned short* vsrc[4];

  auto stage = [&](int buf) {
#pragma unroll
    for (int ch = 0; ch < 4; ++ch) {
      gll16(ksrc[ch], Ks[buf] + dst8[ch]); ksrc[ch] += 64 * 128;
      gll16(vsrc[ch], Vs[buf] + dst8[ch]); vsrc[ch] += 64;
    }
  };

#pragma unroll 1
  for (int qi = 0; qi < 2; ++qi) {
    const int qt = qi ? bx : (31 - bx);

#pragma unroll
    for (int ch = 0; ch < 4; ++ch) { ksrc[ch] = ksrc0[ch]; vsrc[ch] = vsrc0[ch]; }

    bf16x8 qf[4];
#pragma unroll
    for (int kk = 0; kk < 4; ++kk)
      qf[kk] = *reinterpret_cast<const bf16x8*>(
          Qb + ((size_t)(qt * 64 + wid * 16 + lr)) * 128 + kk * 32 + lg * 8);

    f32x4 oacc[8] = {};
    float mrow[4], lsum[4];
#pragma unroll
    for (int r = 0; r < 4; ++r) { mrow[r] = -1e30f; lsum[r] = 0.f; }

    int cur = 0;
    stage(0);

#pragma unroll 1
    for (int kt = 0; kt <= qt; ++kt) {
      if (kt < qt) {
        stage(cur ^ 1);
        asm volatile("s_waitcnt vmcnt(8)" ::: "memory");
      } else {
        asm volatile("s_waitcnt vmcnt(0)" ::: "memory");
      }
      __builtin_amdgcn_s_barrier();
      __builtin_amdgcn_sched_barrier(0);

      float sv[4][4];
#pragma unroll
      for (int nt = 0; nt < 4; ++nt) {
        f32x4 sa = {};
#pragma unroll
        for (int kk = 0; kk < 4; ++kk) {
          int row = nt * 16 + lr;
          bf16x8 kf = *reinterpret_cast<const bf16x8*>(
              Ks[cur] + row * 128 + (((kk * 4 + lg) ^ (row & 7)) << 3));
          sa = __builtin_amdgcn_mfma_f32_16x16x32_bf16(qf[kk], kf, sa, 0, 0, 0);
        }
#pragma unroll
        for (int r = 0; r < 4; ++r) {
          float s = sa[r] * SC2;               // log2-domain score
          if (kt == qt && (nt * 16 + lr) > (wid * 16 + lg * 4 + r)) s -= 1.5e9f;
          sv[nt][r] = s;
        }
      }

      float tmax[4];
#pragma unroll
      for (int r = 0; r < 4; ++r)
        tmax[r] = fmaxf(fmaxf(sv[0][r], sv[1][r]), fmaxf(sv[2][r], sv[3][r]));
#pragma unroll
      for (int r = 0; r < 4; ++r) {
        tmax[r] = fmaxf(tmax[r], __shfl_xor(tmax[r], 1));
        tmax[r] = fmaxf(tmax[r], __shfl_xor(tmax[r], 2));
        tmax[r] = fmaxf(tmax[r], __shfl_xor(tmax[r], 4));
        tmax[r] = fmaxf(tmax[r], __shfl_xor(tmax[r], 8));
      }

      // T13 defer-max (2-domain threshold 8*log2e = 11.54)
      float need = fmaxf(fmaxf(tmax[0] - mrow[0], tmax[1] - mrow[1]),
                         fmaxf(tmax[2] - mrow[2], tmax[3] - mrow[3]));
      if (__any(need > 11.54f)) {
#pragma unroll
        for (int r = 0; r < 4; ++r) {
          float mn = fmaxf(mrow[r], tmax[r]);
          float fr = exp2f(mrow[r] - mn);
          mrow[r] = mn;
          lsum[r] *= fr;
#pragma unroll
          for (int ct = 0; ct < 8; ++ct) oacc[ct][r] *= fr;
        }
      }

      float tsum[4] = {0.f, 0.f, 0.f, 0.f};
#pragma unroll
      for (int nt = 0; nt < 4; ++nt) {
        int colc = nt * 2 + (lr >> 3);
#pragma unroll
        for (int r = 0; r < 4; ++r) {
          float p = exp2f(sv[nt][r] - mrow[r]);
          tsum[r] += p;
          int row = wid * 16 + lg * 4 + r;
          Ps[row * 64 + ((colc ^ (row & 7)) << 3) + (lr & 7)] = f2bf(p);
        }
      }
#pragma unroll
      for (int r = 0; r < 4; ++r) {
        tsum[r] += __shfl_xor(tsum[r], 1);
        tsum[r] += __shfl_xor(tsum[r], 2);
        tsum[r] += __shfl_xor(tsum[r], 4);
        tsum[r] += __shfl_xor(tsum[r], 8);
        lsum[r] += tsum[r];
      }

      bf16x8 pf[2];
#pragma unroll
      for (int ks = 0; ks < 2; ++ks) {
        int row = wid * 16 + lr;
        pf[ks] = *reinterpret_cast<const bf16x8*>(
            Ps + row * 64 + (((ks * 4 + lg) ^ (row & 7)) << 3));
      }
#pragma unroll
      for (int ct = 0; ct < 8; ++ct) {
#pragma unroll
        for (int ks = 0; ks < 2; ++ks) {
          int row = ct * 16 + lr;
          bf16x8 vf = *reinterpret_cast<const bf16x8*>(
              Vs[cur] + row * 64 + (((ks * 4 + lg) ^ (row & 7)) << 3));
          oacc[ct] = __builtin_amdgcn_mfma_f32_16x16x32_bf16(pf[ks], vf, oacc[ct], 0, 0, 0);
        }
      }
      __builtin_amdgcn_s_barrier();
      cur ^= 1;
    }

#pragma unroll
    for (int r = 0; r < 4; ++r) {
      float rl = 1.f / lsum[r];
      int qg = qt * 64 + wid * 16 + lg * 4 + r;
#pragma unroll
      for (int ct = 0; ct < 8; ++ct) {
        int d = ct * 16 + lr;
        attnb[((size_t)b * SS + qg) * HH + h * 128 + d] = f2bf(oacc[ct][r] * rl);
      }
    }
  }
}

// ---------------- launch ----------------

extern "C" void kernel_launch(void* const* d_in, const int* in_sizes, int n_in,
                              void* d_out, int out_size, void* d_ws, size_t ws_size,
                              hipStream_t stream) {
  const float* hs     = (const float*)d_in[0];
  const int*   pos    = (const int*)d_in[1];
  const float* qkv_w  = (const float*)d_in[3];
  const float* qkv_b  = (const float*)d_in[4];
  const float* o_w    = (const float*)d_in[5];
  float* out = (float*)d_out;
  char* ws = (char*)d_ws;

  unsigned short* hsb   = (unsigned short*)(ws);                  // 16 MB
  unsigned short* wqkvb = (unsigned short*)(ws + 16777216);       // 24 MB
  unsigned short* owb   = (unsigned short*)(ws + 41943040);       // 8 MB
  unsigned short* Qr    = (unsigned short*)(ws + 50331648);       // 16 MB
  unsigned short* Kr    = (unsigned short*)(ws + 67108864);       // 16 MB
  unsigned short* Vt    = (unsigned short*)(ws + 83886080);       // 16 MB
  unsigned short* attnb = (unsigned short*)(ws + 100663296);      // 16 MB
  float*          tab   = (float*)(ws + 117440512);               // 1 MB

  convert_bf16<<<2097152 / 256, 256, 0, stream>>>(hs, hsb, 2097152);
  convert_bf16<<<3145728 / 256, 256, 0, stream>>>(qkv_w, wqkvb, 3145728);
  convert_bf16<<<1048576 / 256, 256, 0, stream>>>(o_w, owb, 1048576);
  build_tab<<<512, 256, 0, stream>>>(tab);

  // QKV + fused RoPE: grid 24x16 = 384 blocks.
  gemm_qkv<<<dim3(24, 16), 512, 0, stream>>>(hsb, wqkvb, qkv_b, pos, tab, Qr, Kr, Vt, 2048);
  attn_fwd<<<dim3(16, 32), 256, 0, stream>>>(Qr, Kr, Vt, attnb);
  // O-proj: 128x128 m97-regime, grid 16x32 = 512 blocks.
  gemm97<0><<<dim3(16, 32), 256, 0, stream>>>(attnb, owb, out, 2048);
}